// Round 6
// baseline (367.133 us; speedup 1.0000x reference)
//
#include <hip/hip_runtime.h>
#include <math.h>

#define N_NODES 100000
#define N_EDGES 3200000
#define NBLK_EDGE ((N_EDGES + 255) / 256)
#define NBLK_NODE ((N_NODES + 255) / 256)

#define NB 64                                // nodes per bucket
#define NBUCK ((N_NODES + NB - 1) / NB)      // 1563
#define NSLICE 256
#define SLICE (N_EDGES / NSLICE)             // 12500 exact
#define P2 2048                              // pow2 >= NBUCK for the scan
#define ACCS 72                              // padded channel stride (bank spread)

typedef _Float16 h2f16 __attribute__((ext_vector_type(2)));
typedef __fp16 f16x8 __attribute__((ext_vector_type(8)));   // MFMA operand type
typedef float f32x4 __attribute__((ext_vector_type(4)));
typedef unsigned u32x4 __attribute__((ext_vector_type(4)));

// packed-weight table offsets (h2f16 units)
// All A-fragments for 16x16x32 f16 MFMA: lane(q,c) holds A[row=c, kslot=8q+j].
// Layer2 A is k-permuted by tau(8q+j) = j<4 ? 4q+j : 16+4q+(j-4) so the
// layer1 D-fragment packs in-lane into layer2's B; head A likewise so layer2's
// D packs in-lane into the head's B. tau is a bijection on [0,32).
// Head A rows are CHANNEL-REPLICATED: row r holds channel (r&3) weights, so
// D2[row=4q+r] = channel r on every q — lane(q,c) adds channel q only (one
// 64-lane LDS atomic per group instead of 5 x 16-lane).
#define PK_ENC_A2 0     // 2 tiles x 64 lanes x 4 pairs (W2^T, tau-permuted k)
#define PK_DEC_A2 512
#define PK_ENC_A1 1024  // 2 tiles x 64 lanes x 4 pairs (W1^T, natural k, rows>=8 zero)
#define PK_DEC_A1 1536
#define PK_ENC_HA 2048  // 64 lanes x 4 pairs (head weights, tau-k, channel-replicated rows)
#define PK_DEC_HA 2304
#define PK_TOTAL 2560

__device__ __forceinline__ h2f16 mkh2(float a, float b) {
  h2f16 h;
  h.x = (_Float16)a;
  h.y = (_Float16)b;
  return h;
}
__device__ __forceinline__ h2f16 pk(float a, float b) {
  auto r = __builtin_amdgcn_cvt_pkrtz(a, b);  // v_cvt_pkrtz_f16_f32
  return __builtin_bit_cast(h2f16, r);
}
__device__ __forceinline__ unsigned h2u(h2f16 h) {
  return __builtin_bit_cast(unsigned, h);
}
__device__ __forceinline__ f32x4 mfma16(f16x8 a, f16x8 b, f32x4 c) {
  return __builtin_amdgcn_mfma_f32_16x16x32_f16(a, b, c, 0, 0, 0);
}
__device__ __forceinline__ void atomAddF(float* p, float v) {
  unsafeAtomicAdd(p, v);
}

// ---------------- pack weights into MFMA-fragment-ready tables ----------------
__global__ __launch_bounds__(256) void pack_weights(
    const float* __restrict__ eW1, const float* __restrict__ eW2,
    const float* __restrict__ mW, const float* __restrict__ vW,
    const float* __restrict__ dW1, const float* __restrict__ dW2,
    const float* __restrict__ dW3, h2f16* __restrict__ wpk) {
  int t = threadIdx.x;
  // layer2 A-fragments, tau-permuted k
  for (int i = t; i < 512; i += 256) {
    int tl = i >> 8, rest = i & 255, lane = rest >> 2, p = rest & 3;
    int q = lane >> 4, c = lane & 15;
    int out = 16 * tl + c;
    int k0 = (p < 2) ? (4 * q + 2 * p) : (16 + 4 * q + 2 * (p - 2));  // tau
    wpk[PK_ENC_A2 + i] = mkh2(eW2[k0 * 32 + out], eW2[(k0 + 1) * 32 + out]);
    wpk[PK_DEC_A2 + i] = mkh2(dW2[k0 * 32 + out], dW2[(k0 + 1) * 32 + out]);
  }
  // layer1 A-fragments, natural k (enc: k<8 real, dec: k<4 real, rest zero)
  for (int i = t; i < 512; i += 256) {
    int tl = i >> 8, rest = i & 255, lane = rest >> 2, p = rest & 3;
    int q = lane >> 4, c = lane & 15;
    int out = 16 * tl + c;
    int k0 = 8 * q + 2 * p;
    float w0e = (k0 < 8) ? eW1[k0 * 32 + out] : 0.0f;
    float w1e = (k0 + 1 < 8) ? eW1[(k0 + 1) * 32 + out] : 0.0f;
    float w0d = (k0 < 4) ? dW1[k0 * 32 + out] : 0.0f;
    float w1d = (k0 + 1 < 4) ? dW1[(k0 + 1) * 32 + out] : 0.0f;
    wpk[PK_ENC_A1 + i] = mkh2(w0e, w1e);
    wpk[PK_DEC_A1 + i] = mkh2(w0d, w1d);
  }
  // head A-fragments, tau-permuted k, channel-replicated rows: row c -> ch c&3
  for (int i = t; i < 256; i += 256) {
    int lane = i >> 2, p = i & 3;
    int q = lane >> 4, c = lane & 15;
    int d0 = (p < 2) ? (4 * q + 2 * p) : (16 + 4 * q + 2 * (p - 2));  // tau
    int d1 = d0 + 1;
    int ch = c & 3;
    float e0 = (ch < 2) ? mW[d0 * 2 + ch] : vW[d0 * 2 + (ch - 2)];
    float e1 = (ch < 2) ? mW[d1 * 2 + ch] : vW[d1 * 2 + (ch - 2)];
    float g0 = dW3[d0 * 4 + ch];
    float g1 = dW3[d1 * 4 + ch];
    wpk[PK_ENC_HA + i] = mkh2(e0, e1);
    wpk[PK_DEC_HA + i] = mkh2(g0, g1);
  }
}

// ---------------- BatchNorm statistics ----------------
__global__ void bn_reduce(const float4* __restrict__ x, float* __restrict__ bns) {
  float s0 = 0, s1 = 0, s2 = 0, s3 = 0, q0 = 0, q1 = 0, q2 = 0, q3 = 0;
  for (int i = blockIdx.x * blockDim.x + threadIdx.x; i < N_NODES;
       i += gridDim.x * blockDim.x) {
    float4 v = x[i];
    s0 += v.x; s1 += v.y; s2 += v.z; s3 += v.w;
    q0 += v.x * v.x; q1 += v.y * v.y; q2 += v.z * v.z; q3 += v.w * v.w;
  }
#pragma unroll
  for (int o = 32; o; o >>= 1) {
    s0 += __shfl_down(s0, o); s1 += __shfl_down(s1, o);
    s2 += __shfl_down(s2, o); s3 += __shfl_down(s3, o);
    q0 += __shfl_down(q0, o); q1 += __shfl_down(q1, o);
    q2 += __shfl_down(q2, o); q3 += __shfl_down(q3, o);
  }
  __shared__ float red[4][8];
  int w = threadIdx.x >> 6;
  if ((threadIdx.x & 63) == 0) {
    red[w][0] = s0; red[w][1] = s1; red[w][2] = s2; red[w][3] = s3;
    red[w][4] = q0; red[w][5] = q1; red[w][6] = q2; red[w][7] = q3;
  }
  __syncthreads();
  if (threadIdx.x < 8) {
    float acc = red[0][threadIdx.x] + red[1][threadIdx.x] +
                red[2][threadIdx.x] + red[3][threadIdx.x];
    atomicAdd(&bns[threadIdx.x], acc);
  }
}

__global__ void bn_final(const float* __restrict__ bns,
                         const float* __restrict__ gamma,
                         const float* __restrict__ beta,
                         float* __restrict__ ab) {
  int d = threadIdx.x;
  if (d < 4) {
    float mean = bns[d] * (1.0f / N_NODES);
    float var = bns[4 + d] * (1.0f / N_NODES) - mean * mean;
    float a = gamma[d] * rsqrtf(var + 1e-5f);
    ab[d] = a;
    ab[4 + d] = beta[d] - mean * a;  // xn = a*x + b
  }
}

// ---------------- counting sort by target bucket (no global atomics) -------
__global__ __launch_bounds__(256) void edge_hist(const int* __restrict__ tgt,
                                                 unsigned* __restrict__ hist) {
  __shared__ unsigned h[NBUCK];
  for (int i = threadIdx.x; i < NBUCK; i += 256) h[i] = 0;
  __syncthreads();
  int e0 = blockIdx.x * SLICE;
  for (int i = threadIdx.x; i < SLICE; i += 256)
    atomicAdd(&h[((unsigned)tgt[e0 + i]) >> 6], 1u);
  __syncthreads();
  for (int i = threadIdx.x; i < NBUCK; i += 256)
    hist[(size_t)blockIdx.x * NBUCK + i] = h[i];
}

__global__ __launch_bounds__(256) void bucket_tot(const unsigned* __restrict__ hist,
                                                  unsigned* __restrict__ tot) {
  int k = blockIdx.x * 256 + threadIdx.x;
  if (k >= NBUCK) return;
  unsigned s = 0;
#pragma unroll 8
  for (int b = 0; b < NSLICE; ++b) s += hist[(size_t)b * NBUCK + k];
  tot[k] = s;
}

__global__ __launch_bounds__(1024) void bucket_start(const unsigned* __restrict__ tot,
                                                     unsigned* __restrict__ start) {
  __shared__ unsigned sa[P2], sb[P2];
  for (int k = threadIdx.x; k < P2; k += 1024)
    sa[k] = (k < NBUCK) ? tot[k] : 0u;
  __syncthreads();
  unsigned *srcp = sa, *dstp = sb;
  for (int off = 1; off < P2; off <<= 1) {
    for (int k = threadIdx.x; k < P2; k += 1024)
      dstp[k] = srcp[k] + (k >= off ? srcp[k - off] : 0u);
    __syncthreads();
    unsigned* t = srcp; srcp = dstp; dstp = t;
  }
  for (int k = threadIdx.x; k <= NBUCK; k += 1024)
    start[k] = (k == 0) ? 0u : srcp[k - 1];
}

__global__ __launch_bounds__(256) void bucket_bases(unsigned* __restrict__ hist,
                                                    const unsigned* __restrict__ start) {
  int wv = threadIdx.x >> 6, lane = threadIdx.x & 63;
  int k = blockIdx.x * 4 + wv;
  if (k >= NBUCK) return;
  unsigned v0 = hist[(size_t)(4 * lane + 0) * NBUCK + k];
  unsigned v1 = hist[(size_t)(4 * lane + 1) * NBUCK + k];
  unsigned v2 = hist[(size_t)(4 * lane + 2) * NBUCK + k];
  unsigned v3 = hist[(size_t)(4 * lane + 3) * NBUCK + k];
  unsigned p1 = v0, p2 = v0 + v1, p3 = v0 + v1 + v2;
  unsigned s = p3 + v3;
  unsigned incl = s;
#pragma unroll
  for (int off = 1; off < 64; off <<= 1) {
    unsigned t = __shfl_up(incl, off);
    incl += (lane >= off) ? t : 0u;
  }
  unsigned base = start[k] + (incl - s);
  hist[(size_t)(4 * lane + 0) * NBUCK + k] = base;
  hist[(size_t)(4 * lane + 1) * NBUCK + k] = base + p1;
  hist[(size_t)(4 * lane + 2) * NBUCK + k] = base + p2;
  hist[(size_t)(4 * lane + 3) * NBUCK + k] = base + p3;
}

__global__ __launch_bounds__(256) void edge_place(
    const int* __restrict__ src, const int* __restrict__ tgt,
    const unsigned* __restrict__ hist, const unsigned* __restrict__ start,
    unsigned* __restrict__ payload) {
  __shared__ unsigned stage[SLICE];
  __shared__ unsigned offA[NBUCK];
  __shared__ unsigned A2[NBUCK];
  int s = blockIdx.x, tid = threadIdx.x;
  for (int k = tid; k < NBUCK; k += 256) {
    unsigned gb = hist[(size_t)s * NBUCK + k];
    unsigned nb = (s == NSLICE - 1) ? start[k + 1]
                                    : hist[(size_t)(s + 1) * NBUCK + k];
    offA[k] = gb;
    A2[k] = nb - gb;
  }
  __syncthreads();
  for (int d = 1; d < NBUCK; d <<= 1) {
    unsigned tmp[7];
    int m = 0;
    for (int k = tid; k < NBUCK; k += 256, ++m)
      tmp[m] = (k >= d) ? A2[k - d] : 0u;
    __syncthreads();
    m = 0;
    for (int k = tid; k < NBUCK; k += 256, ++m) A2[k] += tmp[m];
    __syncthreads();
  }
  {
    unsigned tmp[7];
    int m = 0;
    for (int k = tid; k < NBUCK; k += 256, ++m)
      tmp[m] = (k == 0) ? 0u : A2[k - 1];
    __syncthreads();
    m = 0;
    for (int k = tid; k < NBUCK; k += 256, ++m) {
      offA[k] -= tmp[m];
      A2[k] = tmp[m];
    }
    __syncthreads();
  }
  int e0 = s * SLICE;
  for (int i = tid; i < SLICE; i += 256) {
    unsigned t = (unsigned)tgt[e0 + i];
    unsigned sr = (unsigned)src[e0 + i];
    unsigned b = t >> 6;
    unsigned lp = atomicAdd(&A2[b], 1u);
    stage[lp] = sr | ((t & 63u) << 17);
  }
  __syncthreads();
  for (int b = tid; b < NBUCK; b += 256) {
    unsigned beg = (b == 0) ? 0u : A2[b - 1];
    unsigned end = A2[b];
    unsigned go = offA[b];
    for (unsigned i = beg; i < end; ++i) payload[go + i] = stage[i];
  }
}

// ---------------- Encoder EdgeConv: 64 edges/iter, channel-split atomics ---
// min-waves hint 4 (not 8): 8 caps VGPR at 32 -> per-iter scratch spills
// (rounds 2-3: ~100 MB HBM traffic). 4 unrolled edge groups per iteration:
// halves iteration count, 4 independent gathers in flight.
__global__ __launch_bounds__(256, 4) void enc_bucket(
    const float4* __restrict__ x, const unsigned* __restrict__ payload,
    const unsigned* __restrict__ start, const float* __restrict__ ab,
    const float* __restrict__ eb1, const float* __restrict__ eb2,
    const h2f16* __restrict__ wpk, float4* __restrict__ mvpart,
    float* __restrict__ cpart, int nsplit) {
  __shared__ float accS[4 * ACCS];  // ch0=m0 ch1=m1 ch2=v0 ch3=v1, stride 72
  __shared__ float aC[NB];
  __shared__ float4 xt[NB];
  int k = blockIdx.x, node0 = k * NB, h = blockIdx.y;
  int tid = threadIdx.x, w = tid >> 6, lane = tid & 63;
  int q = lane >> 4, c = lane & 15;
  unsigned s0v = start[k], s1v = start[k + 1];
  unsigned len = s1v - s0v, qlen = (len + (unsigned)nsplit - 1u) / (unsigned)nsplit;
  unsigned lo = s0v + (unsigned)h * qlen;
  unsigned hi = lo + qlen;
  if (hi > s1v) hi = s1v;
  for (int i = tid; i < 4 * ACCS; i += 256) accS[i] = 0.0f;
  if (tid < NB) {
    int n = node0 + tid;
    aC[tid] = 0.0f;
    xt[tid] = x[n < N_NODES ? n : 0];
  }
  __syncthreads();
  float a0 = ab[0], a1 = ab[1], a2 = ab[2], a3 = ab[3];
  float b0 = ab[4], b1 = ab[5], b2 = ab[6], b3 = ab[7];
  const u32x4* a2t = (const u32x4*)(wpk + PK_ENC_A2);
  const u32x4* a1t = (const u32x4*)(wpk + PK_ENC_A1);
  const u32x4* hat = (const u32x4*)(wpk + PK_ENC_HA);
  f16x8 A20 = __builtin_bit_cast(f16x8, a2t[lane]);
  f16x8 A21 = __builtin_bit_cast(f16x8, a2t[64 + lane]);
  f16x8 A10 = __builtin_bit_cast(f16x8, a1t[lane]);
  f16x8 A11 = __builtin_bit_cast(f16x8, a1t[64 + lane]);
  f16x8 HA = __builtin_bit_cast(f16x8, hat[lane]);
  float e1a[4], e1b[4], e2a[4], e2b[4];
#pragma unroll
  for (int r = 0; r < 4; ++r) {
    e1a[r] = eb1[4 * q + r];
    e1b[r] = eb1[16 + 4 * q + r];
    e2a[r] = eb2[4 * q + r];
    e2b[r] = eb2[16 + 4 * q + r];
  }
  int qoff = q * ACCS;
  unsigned base = lo + (unsigned)w * 64u;
  if (base < hi) {
    unsigned p[4], pn[4];
    float4 xj[4], xjn[4];
#pragma unroll
    for (int g = 0; g < 4; ++g) {
      unsigned e = base + 16u * g + (unsigned)c;
      e = e < hi ? e : hi - 1u;
      p[g] = payload[e];
    }
#pragma unroll
    for (int g = 0; g < 4; ++g) xj[g] = x[(int)(p[g] & 0x1FFFFu)];
    f32x4 zf = {0.f, 0.f, 0.f, 0.f};
    for (; base < hi; base += 256u) {
      unsigned nb = base + 256u;
#pragma unroll
      for (int g = 0; g < 4; ++g) {
        unsigned e = nb + 16u * g + (unsigned)c;
        e = e < hi ? e : hi - 1u;
        pn[g] = payload[e];
      }
      int lti[4];
      float4 xi[4];
      bool v[4];
#pragma unroll
      for (int g = 0; g < 4; ++g) {
        lti[g] = (int)(p[g] >> 17);
        xi[g] = xt[lti[g]];
        v[g] = (base + 16u * g + (unsigned)c) < hi;
      }
      u32x4 fu[4];
#pragma unroll
      for (int g = 0; g < 4; ++g) {
        fu[g][0] = h2u(pk(fmaf(a0, xi[g].x, b0), fmaf(a1, xi[g].y, b1)));
        fu[g][1] = h2u(pk(fmaf(a2, xi[g].z, b2), fmaf(a3, xi[g].w, b3)));
        fu[g][2] = h2u(pk(a0 * (xj[g].x - xi[g].x), a1 * (xj[g].y - xi[g].y)));
        fu[g][3] = h2u(pk(a2 * (xj[g].z - xi[g].z), a3 * (xj[g].w - xi[g].w)));
      }
      // prefetch next gathers while the MFMA chains run
#pragma unroll
      for (int g = 0; g < 4; ++g) xjn[g] = x[(int)(pn[g] & 0x1FFFFu)];
#pragma unroll
      for (int g = 0; g < 4; ++g) {
        f16x8 F = __builtin_bit_cast(f16x8, fu[g]);
        f32x4 D10 = mfma16(A10, F, zf), D11 = mfma16(A11, F, zf);
        u32x4 h1;
        h1[0] = h2u(pk(fmaxf(D10[0] + e1a[0], 0.f), fmaxf(D10[1] + e1a[1], 0.f)));
        h1[1] = h2u(pk(fmaxf(D10[2] + e1a[2], 0.f), fmaxf(D10[3] + e1a[3], 0.f)));
        h1[2] = h2u(pk(fmaxf(D11[0] + e1b[0], 0.f), fmaxf(D11[1] + e1b[1], 0.f)));
        h1[3] = h2u(pk(fmaxf(D11[2] + e1b[2], 0.f), fmaxf(D11[3] + e1b[3], 0.f)));
        f16x8 B2 = __builtin_bit_cast(f16x8, h1);
        f32x4 C0 = mfma16(A20, B2, zf), C1 = mfma16(A21, B2, zf);
        u32x4 g2;
        g2[0] = h2u(pk(fmaxf(C0[0] + e2a[0], 0.f), fmaxf(C0[1] + e2a[1], 0.f)));
        g2[1] = h2u(pk(fmaxf(C0[2] + e2a[2], 0.f), fmaxf(C0[3] + e2a[3], 0.f)));
        g2[2] = h2u(pk(fmaxf(C1[0] + e2b[0], 0.f), fmaxf(C1[1] + e2b[1], 0.f)));
        g2[3] = h2u(pk(fmaxf(C1[2] + e2b[2], 0.f), fmaxf(C1[3] + e2b[3], 0.f)));
        // head MFMA, channel-replicated: D2[reg r] = channel r on every q
        f32x4 D2 = mfma16(HA, __builtin_bit_cast(f16x8, g2), zf);
        float sv = (q == 0) ? D2[0] : (q == 1) ? D2[1] : (q == 2) ? D2[2] : D2[3];
        if (v[g]) {
          atomicAdd(&accS[qoff + lti[g]], sv);    // 64-lane, q-split channels
          if (lane < 16) atomicAdd(&aC[lti[g]], 1.0f);
        }
      }
#pragma unroll
      for (int g = 0; g < 4; ++g) {
        p[g] = pn[g];
        xj[g] = xjn[g];
      }
    }
  }
  __syncthreads();
  // plain-store partial slice (empty-range blocks store zeros; no memset,
  // no global atomics -> no line-granular RMW traffic)
  if (tid < NB) {
    int n = node0 + tid;
    if (n < N_NODES) {
      mvpart[(size_t)h * N_NODES + n] =
          make_float4(accS[tid], accS[ACCS + tid], accS[2 * ACCS + tid],
                      accS[3 * ACCS + tid]);
      cpart[(size_t)h * N_NODES + n] = aC[tid];
    }
  }
}

// ---------------- reduce partials + mean + bias + reparameterize ----------
__global__ __launch_bounds__(256) void node_mid(
    const float4* __restrict__ mvpart, const float* __restrict__ cpart,
    const float* __restrict__ eps2, const float* __restrict__ mbias,
    const float* __restrict__ vbias, float* __restrict__ z,
    float* __restrict__ cntC, float2* __restrict__ muOut,
    float2* __restrict__ lvOut, int nsplit) {
  int n = blockIdx.x * 256 + threadIdx.x;
  if (n >= N_NODES) return;
  float m0 = 0, m1 = 0, v0 = 0, v1 = 0, cc = 0;
  for (int h = 0; h < nsplit; ++h) {
    float4 t = mvpart[(size_t)h * N_NODES + n];
    m0 += t.x; m1 += t.y; v0 += t.z; v1 += t.w;
    cc += cpart[(size_t)h * N_NODES + n];
  }
  float inv = 1.0f / fmaxf(cc, 1.0f);
  float mu0 = fmaf(m0, inv, mbias[0]);
  float mu1 = fmaf(m1, inv, mbias[1]);
  float lv0 = fmaf(v0, inv, vbias[0]);
  float lv1 = fmaf(v1, inv, vbias[1]);
  cntC[n] = cc;
  muOut[n] = make_float2(mu0, mu1);
  lvOut[n] = make_float2(lv0, lv1);
  z[2 * n + 0] = fmaf(eps2[2 * n + 0], expf(0.5f * lv0), mu0);
  z[2 * n + 1] = fmaf(eps2[2 * n + 1], expf(0.5f * lv1), mu1);
}

// ---------------- Decoder EdgeConv: 64 edges/iter, channel-split atomics ---
__global__ __launch_bounds__(256, 4) void dec_bucket(
    const float2* __restrict__ z, const unsigned* __restrict__ payload,
    const unsigned* __restrict__ start, const float* __restrict__ db1,
    const float* __restrict__ db2, const h2f16* __restrict__ wpk,
    float4* __restrict__ opart, int nsplit) {
  __shared__ float accO[4 * ACCS];  // ch0..ch3 = o0..o3, stride 72
  __shared__ float2 zt[NB];
  int k = blockIdx.x, node0 = k * NB, h = blockIdx.y;
  int tid = threadIdx.x, w = tid >> 6, lane = tid & 63;
  int q = lane >> 4, c = lane & 15;
  unsigned s0v = start[k], s1v = start[k + 1];
  unsigned len = s1v - s0v, qlen = (len + (unsigned)nsplit - 1u) / (unsigned)nsplit;
  unsigned lo = s0v + (unsigned)h * qlen;
  unsigned hi = lo + qlen;
  if (hi > s1v) hi = s1v;
  for (int i = tid; i < 4 * ACCS; i += 256) accO[i] = 0.0f;
  if (tid < NB) {
    int n = node0 + tid;
    zt[tid] = z[n < N_NODES ? n : 0];
  }
  __syncthreads();
  const u32x4* a2t = (const u32x4*)(wpk + PK_DEC_A2);
  const u32x4* a1t = (const u32x4*)(wpk + PK_DEC_A1);
  const u32x4* hat = (const u32x4*)(wpk + PK_DEC_HA);
  f16x8 A20 = __builtin_bit_cast(f16x8, a2t[lane]);
  f16x8 A21 = __builtin_bit_cast(f16x8, a2t[64 + lane]);
  f16x8 A10 = __builtin_bit_cast(f16x8, a1t[lane]);
  f16x8 A11 = __builtin_bit_cast(f16x8, a1t[64 + lane]);
  f16x8 HA = __builtin_bit_cast(f16x8, hat[lane]);
  float e1a[4], e1b[4], e2a[4], e2b[4];
#pragma unroll
  for (int r = 0; r < 4; ++r) {
    e1a[r] = db1[4 * q + r];
    e1b[r] = db1[16 + 4 * q + r];
    e2a[r] = db2[4 * q + r];
    e2b[r] = db2[16 + 4 * q + r];
  }
  int qoff = q * ACCS;
  unsigned base = lo + (unsigned)w * 64u;
  if (base < hi) {
    unsigned p[4], pn[4];
    float2 zj[4], zjn[4];
#pragma unroll
    for (int g = 0; g < 4; ++g) {
      unsigned e = base + 16u * g + (unsigned)c;
      e = e < hi ? e : hi - 1u;
      p[g] = payload[e];
    }
#pragma unroll
    for (int g = 0; g < 4; ++g) zj[g] = z[(int)(p[g] & 0x1FFFFu)];
    f32x4 zf = {0.f, 0.f, 0.f, 0.f};
    for (; base < hi; base += 256u) {
      unsigned nb = base + 256u;
#pragma unroll
      for (int g = 0; g < 4; ++g) {
        unsigned e = nb + 16u * g + (unsigned)c;
        e = e < hi ? e : hi - 1u;
        pn[g] = payload[e];
      }
      int lti[4];
      float2 zi[4];
      bool v[4];
#pragma unroll
      for (int g = 0; g < 4; ++g) {
        lti[g] = (int)(p[g] >> 17);
        zi[g] = zt[lti[g]];
        v[g] = (base + 16u * g + (unsigned)c) < hi;
      }
      u32x4 fu[4];
#pragma unroll
      for (int g = 0; g < 4; ++g) {
        fu[g][0] = h2u(pk(zi[g].x, zi[g].y));
        fu[g][1] = h2u(pk(zj[g].x - zi[g].x, zj[g].y - zi[g].y));
        fu[g][2] = fu[g][0];
        fu[g][3] = fu[g][1];
      }
#pragma unroll
      for (int g = 0; g < 4; ++g) zjn[g] = z[(int)(pn[g] & 0x1FFFFu)];
#pragma unroll
      for (int g = 0; g < 4; ++g) {
        f16x8 F = __builtin_bit_cast(f16x8, fu[g]);
        f32x4 D10 = mfma16(A10, F, zf), D11 = mfma16(A11, F, zf);
        u32x4 h1;
        h1[0] = h2u(pk(fmaxf(D10[0] + e1a[0], 0.f), fmaxf(D10[1] + e1a[1], 0.f)));
        h1[1] = h2u(pk(fmaxf(D10[2] + e1a[2], 0.f), fmaxf(D10[3] + e1a[3], 0.f)));
        h1[2] = h2u(pk(fmaxf(D11[0] + e1b[0], 0.f), fmaxf(D11[1] + e1b[1], 0.f)));
        h1[3] = h2u(pk(fmaxf(D11[2] + e1b[2], 0.f), fmaxf(D11[3] + e1b[3], 0.f)));
        f16x8 B2 = __builtin_bit_cast(f16x8, h1);
        f32x4 C0 = mfma16(A20, B2, zf), C1 = mfma16(A21, B2, zf);
        u32x4 g2;
        g2[0] = h2u(pk(fmaxf(C0[0] + e2a[0], 0.f), fmaxf(C0[1] + e2a[1], 0.f)));
        g2[1] = h2u(pk(fmaxf(C0[2] + e2a[2], 0.f), fmaxf(C0[3] + e2a[3], 0.f)));
        g2[2] = h2u(pk(fmaxf(C1[0] + e2b[0], 0.f), fmaxf(C1[1] + e2b[1], 0.f)));
        g2[3] = h2u(pk(fmaxf(C1[2] + e2b[2], 0.f), fmaxf(C1[3] + e2b[3], 0.f)));
        f32x4 D2 = mfma16(HA, __builtin_bit_cast(f16x8, g2), zf);
        float sv = (q == 0) ? D2[0] : (q == 1) ? D2[1] : (q == 2) ? D2[2] : D2[3];
        if (v[g]) atomicAdd(&accO[qoff + lti[g]], sv);
      }
#pragma unroll
      for (int g = 0; g < 4; ++g) {
        p[g] = pn[g];
        zj[g] = zjn[g];
      }
    }
  }
  __syncthreads();
  if (tid < NB) {
    int n = node0 + tid;
    if (n < N_NODES)
      opart[(size_t)h * N_NODES + n] =
          make_float4(accO[tid], accO[ACCS + tid], accO[2 * ACCS + tid],
                      accO[3 * ACCS + tid]);
  }
}

__global__ __launch_bounds__(256) void node_final(
    const float4* __restrict__ opart, const float* __restrict__ cntC,
    const float* __restrict__ db3, float4* __restrict__ outp, int nsplit) {
  int n = blockIdx.x * 256 + threadIdx.x;
  if (n >= N_NODES) return;
  float o0 = 0, o1 = 0, o2 = 0, o3 = 0;
  for (int h = 0; h < nsplit; ++h) {
    float4 t = opart[(size_t)h * N_NODES + n];
    o0 += t.x; o1 += t.y; o2 += t.z; o3 += t.w;
  }
  float cc = cntC[n];
  if (cc > 0.0f) {
    float inv = 1.0f / cc;
    outp[n] = make_float4(fmaf(o0, inv, db3[0]), fmaf(o1, inv, db3[1]),
                          fmaf(o2, inv, db3[2]), fmaf(o3, inv, db3[3]));
  } else {
    outp[n] = make_float4(0.f, 0.f, 0.f, 0.f);
  }
}

// ---------------- fallback (device-scope atomics, fp32, round-1 proven) ----
__global__ __launch_bounds__(256) void enc_edge_fb(
    const float4* __restrict__ x, const int* __restrict__ esrc,
    const int* __restrict__ etgt, const float* __restrict__ ab,
    const float* __restrict__ eW1, const float* __restrict__ eb1,
    const float* __restrict__ eW2, const float* __restrict__ eb2,
    const float* __restrict__ mW, const float* __restrict__ vW,
    float* __restrict__ msum, float* __restrict__ vsum,
    float* __restrict__ cnt) {
  int e = blockIdx.x * 256 + threadIdx.x;
  if (e >= N_EDGES) return;
  int si = esrc[e], ti = etgt[e];
  float4 xi = x[ti];
  float4 xj = x[si];
  float a0 = ab[0], a1 = ab[1], a2 = ab[2], a3 = ab[3];
  float b0 = ab[4], b1 = ab[5], b2 = ab[6], b3 = ab[7];
  float feat[8];
  feat[0] = fmaf(a0, xi.x, b0);
  feat[1] = fmaf(a1, xi.y, b1);
  feat[2] = fmaf(a2, xi.z, b2);
  feat[3] = fmaf(a3, xi.w, b3);
  feat[4] = a0 * (xj.x - xi.x);
  feat[5] = a1 * (xj.y - xi.y);
  feat[6] = a2 * (xj.z - xi.z);
  feat[7] = a3 * (xj.w - xi.w);
  float h1[32];
#pragma unroll 8
  for (int j = 0; j < 32; ++j) {
    float acc = eb1[j];
#pragma unroll
    for (int kk = 0; kk < 8; ++kk) acc = fmaf(feat[kk], eW1[kk * 32 + j], acc);
    h1[j] = fmaxf(acc, 0.0f);
  }
  float m0 = 0, m1 = 0, v0 = 0, v1 = 0;
#pragma unroll 4
  for (int j = 0; j < 32; ++j) {
    float acc = eb2[j];
#pragma unroll
    for (int kk = 0; kk < 32; ++kk) acc = fmaf(h1[kk], eW2[kk * 32 + j], acc);
    float h2 = fmaxf(acc, 0.0f);
    m0 = fmaf(h2, mW[j * 2 + 0], m0);
    m1 = fmaf(h2, mW[j * 2 + 1], m1);
    v0 = fmaf(h2, vW[j * 2 + 0], v0);
    v1 = fmaf(h2, vW[j * 2 + 1], v1);
  }
  atomAddF(&msum[ti * 2 + 0], m0);
  atomAddF(&msum[ti * 2 + 1], m1);
  atomAddF(&vsum[ti * 2 + 0], v0);
  atomAddF(&vsum[ti * 2 + 1], v1);
  atomAddF(&cnt[ti], 1.0f);
}

__global__ __launch_bounds__(256) void dec_edge_fb(
    const float2* __restrict__ z, const int* __restrict__ esrc,
    const int* __restrict__ etgt, const float* __restrict__ dW1,
    const float* __restrict__ db1, const float* __restrict__ dW2,
    const float* __restrict__ db2, const float* __restrict__ dW3,
    const float* __restrict__ db3, float* __restrict__ osum) {
  int e = blockIdx.x * 256 + threadIdx.x;
  if (e >= N_EDGES) return;
  int si = esrc[e], ti = etgt[e];
  float2 zi = z[ti], zj = z[si];
  float f0 = zi.x, f1 = zi.y, f2 = zj.x - zi.x, f3 = zj.y - zi.y;
  float h1[32];
#pragma unroll 8
  for (int j = 0; j < 32; ++j) {
    float acc = db1[j];
    acc = fmaf(f0, dW1[0 * 32 + j], acc);
    acc = fmaf(f1, dW1[1 * 32 + j], acc);
    acc = fmaf(f2, dW1[2 * 32 + j], acc);
    acc = fmaf(f3, dW1[3 * 32 + j], acc);
    h1[j] = fmaxf(acc, 0.0f);
  }
  float o0 = db3[0], o1 = db3[1], o2 = db3[2], o3 = db3[3];
#pragma unroll 4
  for (int j = 0; j < 32; ++j) {
    float acc = db2[j];
#pragma unroll
    for (int kk = 0; kk < 32; ++kk) acc = fmaf(h1[kk], dW2[kk * 32 + j], acc);
    float h2 = fmaxf(acc, 0.0f);
    o0 = fmaf(h2, dW3[j * 4 + 0], o0);
    o1 = fmaf(h2, dW3[j * 4 + 1], o1);
    o2 = fmaf(h2, dW3[j * 4 + 2], o2);
    o3 = fmaf(h2, dW3[j * 4 + 3], o3);
  }
  atomAddF(&osum[4 * ti + 0], o0);
  atomAddF(&osum[4 * ti + 1], o1);
  atomAddF(&osum[4 * ti + 2], o2);
  atomAddF(&osum[4 * ti + 3], o3);
}

__global__ __launch_bounds__(256) void node_mid_fb(
    float* __restrict__ msum, float* __restrict__ vsum,
    const float* __restrict__ cnt, const float* __restrict__ eps2,
    const float* __restrict__ mb, const float* __restrict__ vb,
    float* __restrict__ z) {
  int n = blockIdx.x * 256 + threadIdx.x;
  if (n >= N_NODES) return;
  float inv = 1.0f / fmaxf(cnt[n], 1.0f);
  float mu0 = fmaf(msum[2 * n + 0], inv, mb[0]);
  float mu1 = fmaf(msum[2 * n + 1], inv, mb[1]);
  float lv0 = fmaf(vsum[2 * n + 0], inv, vb[0]);
  float lv1 = fmaf(vsum[2 * n + 1], inv, vb[1]);
  msum[2 * n + 0] = mu0;
  msum[2 * n + 1] = mu1;
  vsum[2 * n + 0] = lv0;
  vsum[2 * n + 1] = lv1;
  z[2 * n + 0] = fmaf(eps2[2 * n + 0], expf(0.5f * lv0), mu0);
  z[2 * n + 1] = fmaf(eps2[2 * n + 1], expf(0.5f * lv1), mu1);
}

__global__ __launch_bounds__(256) void node_final_fb(
    float* __restrict__ osum, const float* __restrict__ cnt) {
  int n = blockIdx.x * 256 + threadIdx.x;
  if (n >= N_NODES) return;
  float inv = 1.0f / fmaxf(cnt[n], 1.0f);
  float4* o4 = (float4*)osum;
  float4 v = o4[n];
  v.x *= inv; v.y *= inv; v.z *= inv; v.w *= inv;
  o4[n] = v;
}

extern "C" void kernel_launch(void* const* d_in, const int* in_sizes, int n_in,
                              void* d_out, int out_size, void* d_ws,
                              size_t ws_size, hipStream_t stream) {
  const float* x = (const float*)d_in[0];
  const int* ei = (const int*)d_in[1];
  const float* eps = (const float*)d_in[2];
  const float* bng = (const float*)d_in[3];
  const float* bnb = (const float*)d_in[4];
  const float* eW1 = (const float*)d_in[5];
  const float* eb1 = (const float*)d_in[6];
  const float* eW2 = (const float*)d_in[7];
  const float* eb2 = (const float*)d_in[8];
  const float* mW = (const float*)d_in[9];
  const float* mb = (const float*)d_in[10];
  const float* vW = (const float*)d_in[11];
  const float* vb = (const float*)d_in[12];
  const float* dW1 = (const float*)d_in[13];
  const float* db1 = (const float*)d_in[14];
  const float* dW2 = (const float*)d_in[15];
  const float* db2 = (const float*)d_in[16];
  const float* dW3 = (const float*)d_in[17];
  const float* db3 = (const float*)d_in[18];

  float* out = (float*)d_out;  // [N,4] out | [N,2] mu | [N,2] logvar
  const size_t N = N_NODES;

  const size_t sortBytes =
      ((size_t)(NBUCK + 1) + (size_t)NSLICE * NBUCK + N_EDGES + PK_TOTAL) *
      sizeof(unsigned);
  // floats: 16 hdr + z 2N + cntC N + mvpart 4sN + cpart sN + opart 4sN
  auto reqFor = [&](int s) {
    return (16 + 3 * N + 9 * (size_t)s * N) * sizeof(float) + sortBytes;
  };
  int ns = 0;
  if (ws_size >= reqFor(2)) ns = 2;
  else if (ws_size >= reqFor(1)) ns = 1;

  float* wsf = (float*)d_ws;
  float* bns = wsf;                          // 8
  float* ab = wsf + 8;                       // 8
  float* z = wsf + 16;                       // 2N
  float* cntC = z + 2 * N;                   // N
  float4* mvpart = (float4*)(cntC + N);      // ns*N float4
  float* cpart = (float*)(mvpart + (size_t)ns * N);  // ns*N
  float4* opart = (float4*)(cpart + (size_t)ns * N); // ns*N float4
  unsigned* start = (unsigned*)((float*)opart + 4 * (size_t)ns * N);  // NBUCK+1
  unsigned* hist = start + (NBUCK + 1);                  // NSLICE*NBUCK
  unsigned* payload = hist + (size_t)NSLICE * NBUCK;     // N_EDGES
  h2f16* wpk = (h2f16*)(payload + N_EDGES);              // PK_TOTAL

  if (ns > 0) {
    (void)hipMemsetAsync(bns, 0, 8 * sizeof(float), stream);
    pack_weights<<<1, 256, 0, stream>>>(eW1, eW2, mW, vW, dW1, dW2, dW3, wpk);
    bn_reduce<<<256, 256, 0, stream>>>((const float4*)x, bns);
    bn_final<<<1, 64, 0, stream>>>(bns, bng, bnb, ab);
    edge_hist<<<NSLICE, 256, 0, stream>>>(ei + N_EDGES, hist);
    bucket_tot<<<(NBUCK + 255) / 256, 256, 0, stream>>>(hist, payload);
    bucket_start<<<1, 1024, 0, stream>>>(payload, start);
    bucket_bases<<<(NBUCK + 3) / 4, 256, 0, stream>>>(hist, start);
    edge_place<<<NSLICE, 256, 0, stream>>>(ei, ei + N_EDGES, hist, start,
                                           payload);
    dim3 gE(NBUCK, ns);
    enc_bucket<<<gE, 256, 0, stream>>>((const float4*)x, payload, start, ab,
                                       eb1, eb2, wpk, mvpart, cpart, ns);
    node_mid<<<NBLK_NODE, 256, 0, stream>>>(mvpart, cpart, eps, mb, vb, z,
                                            cntC, (float2*)(out + 4 * N),
                                            (float2*)(out + 6 * N), ns);
    dec_bucket<<<gE, 256, 0, stream>>>((const float2*)z, payload, start, db1,
                                       db2, wpk, opart, ns);
    node_final<<<NBLK_NODE, 256, 0, stream>>>(opart, cntC, db3, (float4*)out,
                                              ns);
  } else {
    // fallback: device-scope atomics (round-1 proven path)
    float* cntf = wsf + 16;       // N
    float* zf = wsf + 16 + N;     // 2N
    float* msum = out + 4 * N;
    float* vsum = out + 6 * N;
    (void)hipMemsetAsync(d_out, 0, 8 * N * sizeof(float), stream);
    (void)hipMemsetAsync(d_ws, 0, (16 + N) * sizeof(float), stream);
    bn_reduce<<<256, 256, 0, stream>>>((const float4*)x, bns);
    bn_final<<<1, 64, 0, stream>>>(bns, bng, bnb, ab);
    enc_edge_fb<<<NBLK_EDGE, 256, 0, stream>>>((const float4*)x, ei,
                                               ei + N_EDGES, ab, eW1, eb1, eW2,
                                               eb2, mW, vW, msum, vsum, cntf);
    node_mid_fb<<<NBLK_NODE, 256, 0, stream>>>(msum, vsum, cntf, eps, mb, vb,
                                               zf);
    dec_edge_fb<<<NBLK_EDGE, 256, 0, stream>>>((const float2*)zf, ei,
                                               ei + N_EDGES, dW1, db1, dW2, db2,
                                               dW3, db3, out);
    node_final_fb<<<NBLK_NODE, 256, 0, stream>>>(out, cntf);
  }
}

// Round 7
// 355.459 us; speedup vs baseline: 1.0328x; 1.0328x over previous
//
#include <hip/hip_runtime.h>
#include <math.h>

#define N_NODES 100000
#define N_EDGES 3200000
#define NBLK_EDGE ((N_EDGES + 255) / 256)
#define NBLK_NODE ((N_NODES + 255) / 256)

#define NB 64                                // nodes per bucket
#define NBUCK ((N_NODES + NB - 1) / NB)      // 1563
#define NSLICE 256
#define SLICE (N_EDGES / NSLICE)             // 12500 exact

typedef _Float16 h2f16 __attribute__((ext_vector_type(2)));
typedef __fp16 f16x8 __attribute__((ext_vector_type(8)));   // MFMA operand type
typedef float f32x4 __attribute__((ext_vector_type(4)));
typedef unsigned u32x4 __attribute__((ext_vector_type(4)));

// packed-weight table offsets (h2f16 units)
// All A-fragments for 16x16x32 f16 MFMA: lane(q,c) holds A[row=c, kslot=8q+j].
// Layer2 A is k-permuted by tau(8q+j) = j<4 ? 4q+j : 16+4q+(j-4) so the
// layer1 D-fragment packs in-lane into layer2's B; head A likewise so layer2's
// D packs in-lane into the head's B. tau is a bijection on [0,32).
#define PK_ENC_A2 0     // 2 tiles x 64 lanes x 4 pairs (W2^T, tau-permuted k)
#define PK_DEC_A2 512
#define PK_ENC_A1 1024  // 2 tiles x 64 lanes x 4 pairs (W1^T, natural k, rows>=8 zero)
#define PK_DEC_A1 1536
#define PK_ENC_HA 2048  // 64 lanes x 4 pairs (head weights, tau-permuted k, rows>=4 zero)
#define PK_DEC_HA 2304
#define PK_TOTAL 2560

__device__ __forceinline__ h2f16 mkh2(float a, float b) {
  h2f16 h;
  h.x = (_Float16)a;
  h.y = (_Float16)b;
  return h;
}
__device__ __forceinline__ h2f16 pk(float a, float b) {
  auto r = __builtin_amdgcn_cvt_pkrtz(a, b);  // v_cvt_pkrtz_f16_f32
  return __builtin_bit_cast(h2f16, r);
}
__device__ __forceinline__ unsigned h2u(h2f16 h) {
  return __builtin_bit_cast(unsigned, h);
}
__device__ __forceinline__ f32x4 mfma16(f16x8 a, f16x8 b, f32x4 c) {
  return __builtin_amdgcn_mfma_f32_16x16x32_f16(a, b, c, 0, 0, 0);
}
__device__ __forceinline__ void atomAddF(float* p, float v) {
  unsafeAtomicAdd(p, v);
}

// ---------------- pack weights into MFMA-fragment-ready tables ----------------
__global__ __launch_bounds__(256) void pack_weights(
    const float* __restrict__ eW1, const float* __restrict__ eW2,
    const float* __restrict__ mW, const float* __restrict__ vW,
    const float* __restrict__ dW1, const float* __restrict__ dW2,
    const float* __restrict__ dW3, h2f16* __restrict__ wpk) {
  int t = threadIdx.x;
  // layer2 A-fragments, tau-permuted k
  for (int i = t; i < 512; i += 256) {
    int tl = i >> 8, rest = i & 255, lane = rest >> 2, p = rest & 3;
    int q = lane >> 4, c = lane & 15;
    int out = 16 * tl + c;
    int k0 = (p < 2) ? (4 * q + 2 * p) : (16 + 4 * q + 2 * (p - 2));  // tau
    wpk[PK_ENC_A2 + i] = mkh2(eW2[k0 * 32 + out], eW2[(k0 + 1) * 32 + out]);
    wpk[PK_DEC_A2 + i] = mkh2(dW2[k0 * 32 + out], dW2[(k0 + 1) * 32 + out]);
  }
  // layer1 A-fragments, natural k (enc: k<8 real, dec: k<4 real, rest zero)
  for (int i = t; i < 512; i += 256) {
    int tl = i >> 8, rest = i & 255, lane = rest >> 2, p = rest & 3;
    int q = lane >> 4, c = lane & 15;
    int out = 16 * tl + c;
    int k0 = 8 * q + 2 * p;
    float w0e = (k0 < 8) ? eW1[k0 * 32 + out] : 0.0f;
    float w1e = (k0 + 1 < 8) ? eW1[(k0 + 1) * 32 + out] : 0.0f;
    float w0d = (k0 < 4) ? dW1[k0 * 32 + out] : 0.0f;
    float w1d = (k0 + 1 < 4) ? dW1[(k0 + 1) * 32 + out] : 0.0f;
    wpk[PK_ENC_A1 + i] = mkh2(w0e, w1e);
    wpk[PK_DEC_A1 + i] = mkh2(w0d, w1d);
  }
  // head A-fragments, tau-permuted k, out-channel = row c (rows>=4 zero)
  for (int i = t; i < 256; i += 256) {
    int lane = i >> 2, p = i & 3;
    int q = lane >> 4, c = lane & 15;
    int d0 = (p < 2) ? (4 * q + 2 * p) : (16 + 4 * q + 2 * (p - 2));  // tau
    int d1 = d0 + 1;
    float e0 = 0.f, e1 = 0.f, g0 = 0.f, g1 = 0.f;
    if (c < 4) {
      e0 = (c < 2) ? mW[d0 * 2 + c] : vW[d0 * 2 + (c - 2)];
      e1 = (c < 2) ? mW[d1 * 2 + c] : vW[d1 * 2 + (c - 2)];
      g0 = dW3[d0 * 4 + c];
      g1 = dW3[d1 * 4 + c];
    }
    wpk[PK_ENC_HA + i] = mkh2(e0, e1);
    wpk[PK_DEC_HA + i] = mkh2(g0, g1);
  }
}

// ---------------- BatchNorm statistics ----------------
__global__ void bn_reduce(const float4* __restrict__ x, float* __restrict__ bns) {
  float s0 = 0, s1 = 0, s2 = 0, s3 = 0, q0 = 0, q1 = 0, q2 = 0, q3 = 0;
  for (int i = blockIdx.x * blockDim.x + threadIdx.x; i < N_NODES;
       i += gridDim.x * blockDim.x) {
    float4 v = x[i];
    s0 += v.x; s1 += v.y; s2 += v.z; s3 += v.w;
    q0 += v.x * v.x; q1 += v.y * v.y; q2 += v.z * v.z; q3 += v.w * v.w;
  }
#pragma unroll
  for (int o = 32; o; o >>= 1) {
    s0 += __shfl_down(s0, o); s1 += __shfl_down(s1, o);
    s2 += __shfl_down(s2, o); s3 += __shfl_down(s3, o);
    q0 += __shfl_down(q0, o); q1 += __shfl_down(q1, o);
    q2 += __shfl_down(q2, o); q3 += __shfl_down(q3, o);
  }
  __shared__ float red[4][8];
  int w = threadIdx.x >> 6;
  if ((threadIdx.x & 63) == 0) {
    red[w][0] = s0; red[w][1] = s1; red[w][2] = s2; red[w][3] = s3;
    red[w][4] = q0; red[w][5] = q1; red[w][6] = q2; red[w][7] = q3;
  }
  __syncthreads();
  if (threadIdx.x < 8) {
    float acc = red[0][threadIdx.x] + red[1][threadIdx.x] +
                red[2][threadIdx.x] + red[3][threadIdx.x];
    atomicAdd(&bns[threadIdx.x], acc);
  }
}

__global__ void bn_final(const float* __restrict__ bns,
                         const float* __restrict__ gamma,
                         const float* __restrict__ beta,
                         float* __restrict__ ab) {
  int d = threadIdx.x;
  if (d < 4) {
    float mean = bns[d] * (1.0f / N_NODES);
    float var = bns[4 + d] * (1.0f / N_NODES) - mean * mean;
    float a = gamma[d] * rsqrtf(var + 1e-5f);
    ab[d] = a;
    ab[4 + d] = beta[d] - mean * a;  // xn = a*x + b
  }
}

// ---------------- counting sort by target bucket ----------------
// edge_hist also accumulates column totals (tot) via global atomics,
// replacing the old 7-block bucket_tot straggler kernel.
__global__ __launch_bounds__(256) void edge_hist(const int* __restrict__ tgt,
                                                 unsigned* __restrict__ hist,
                                                 unsigned* __restrict__ tot) {
  __shared__ unsigned h[NBUCK];
  for (int i = threadIdx.x; i < NBUCK; i += 256) h[i] = 0;
  __syncthreads();
  int e0 = blockIdx.x * SLICE;
  for (int i = threadIdx.x; i < SLICE; i += 256)
    atomicAdd(&h[((unsigned)tgt[e0 + i]) >> 6], 1u);
  __syncthreads();
  for (int i = threadIdx.x; i < NBUCK; i += 256) {
    unsigned hv = h[i];
    hist[(size_t)blockIdx.x * NBUCK + i] = hv;
    if (hv) atomicAdd(&tot[i], hv);
  }
}

// 3-level scan (wave shfl + cross-wave), 2 barriers instead of 22.
__global__ __launch_bounds__(1024) void bucket_start(const unsigned* __restrict__ tot,
                                                     unsigned* __restrict__ start) {
  __shared__ unsigned wsum[16];
  int tid = threadIdx.x, lane = tid & 63, wid = tid >> 6;
  int k0 = 2 * tid;
  unsigned v0 = (k0 < NBUCK) ? tot[k0] : 0u;
  unsigned v1 = (k0 + 1 < NBUCK) ? tot[k0 + 1] : 0u;
  unsigned s = v0 + v1, incl = s;
#pragma unroll
  for (int off = 1; off < 64; off <<= 1) {
    unsigned t = __shfl_up(incl, off);
    incl += (lane >= off) ? t : 0u;
  }
  if (lane == 63) wsum[wid] = incl;
  __syncthreads();
  if (tid == 0) {
    unsigned a = 0;
#pragma unroll
    for (int w2 = 0; w2 < 16; ++w2) {
      unsigned t = wsum[w2];
      wsum[w2] = a;
      a += t;
    }
  }
  __syncthreads();
  unsigned excl0 = wsum[wid] + incl - s;
  if (k0 <= NBUCK) start[k0] = excl0;
  if (k0 + 1 <= NBUCK) start[k0 + 1] = excl0 + v0;
}

__global__ __launch_bounds__(256) void bucket_bases(unsigned* __restrict__ hist,
                                                    const unsigned* __restrict__ start) {
  int wv = threadIdx.x >> 6, lane = threadIdx.x & 63;
  int k = blockIdx.x * 4 + wv;
  if (k >= NBUCK) return;
  unsigned v0 = hist[(size_t)(4 * lane + 0) * NBUCK + k];
  unsigned v1 = hist[(size_t)(4 * lane + 1) * NBUCK + k];
  unsigned v2 = hist[(size_t)(4 * lane + 2) * NBUCK + k];
  unsigned v3 = hist[(size_t)(4 * lane + 3) * NBUCK + k];
  unsigned p1 = v0, p2 = v0 + v1, p3 = v0 + v1 + v2;
  unsigned s = p3 + v3;
  unsigned incl = s;
#pragma unroll
  for (int off = 1; off < 64; off <<= 1) {
    unsigned t = __shfl_up(incl, off);
    incl += (lane >= off) ? t : 0u;
  }
  unsigned base = start[k] + (incl - s);
  hist[(size_t)(4 * lane + 0) * NBUCK + k] = base;
  hist[(size_t)(4 * lane + 1) * NBUCK + k] = base + p1;
  hist[(size_t)(4 * lane + 2) * NBUCK + k] = base + p2;
  hist[(size_t)(4 * lane + 3) * NBUCK + k] = base + p3;
}

__global__ __launch_bounds__(256) void edge_place(
    const int* __restrict__ src, const int* __restrict__ tgt,
    const unsigned* __restrict__ hist, const unsigned* __restrict__ start,
    unsigned* __restrict__ payload) {
  __shared__ unsigned stage[SLICE];
  __shared__ unsigned offA[NBUCK];
  __shared__ unsigned A2[NBUCK];
  __shared__ unsigned tsum[4];
  int s = blockIdx.x, tid = threadIdx.x;
  for (int k = tid; k < NBUCK; k += 256) {
    unsigned gb = hist[(size_t)s * NBUCK + k];
    unsigned nb = (s == NSLICE - 1) ? start[k + 1]
                                    : hist[(size_t)(s + 1) * NBUCK + k];
    offA[k] = gb;
    A2[k] = nb - gb;
  }
  __syncthreads();
  // exclusive scan of A2 in place: contiguous 7 elems/thread + wave shfl +
  // cross-wave (2 barriers, replaces the 33-barrier Hillis-Steele)
  {
    int lane = tid & 63, wid = tid >> 6;
    int t0 = tid * 7;
    unsigned v[7], run = 0;
#pragma unroll
    for (int m = 0; m < 7; ++m) {
      int k = t0 + m;
      v[m] = (k < NBUCK) ? A2[k] : 0u;
      run += v[m];
    }
    unsigned incl = run;
#pragma unroll
    for (int off = 1; off < 64; off <<= 1) {
      unsigned t = __shfl_up(incl, off);
      incl += (lane >= off) ? t : 0u;
    }
    if (lane == 63) tsum[wid] = incl;
    __syncthreads();
    unsigned wbase = 0;
    for (int w2 = 0; w2 < wid; ++w2) wbase += tsum[w2];
    unsigned acc = wbase + incl - run;  // exclusive prefix of elem t0
#pragma unroll
    for (int m = 0; m < 7; ++m) {
      int k = t0 + m;
      if (k < NBUCK) {
        offA[k] -= acc;
        A2[k] = acc;
        acc += v[m];
      }
    }
    __syncthreads();
  }
  int e0 = s * SLICE;
  for (int i = tid; i < SLICE; i += 256) {
    unsigned t = (unsigned)tgt[e0 + i];
    unsigned sr = (unsigned)src[e0 + i];
    unsigned b = t >> 6;
    unsigned lp = atomicAdd(&A2[b], 1u);
    stage[lp] = sr | ((t & 63u) << 17);
  }
  __syncthreads();
  for (int b = tid; b < NBUCK; b += 256) {
    unsigned beg = (b == 0) ? 0u : A2[b - 1];
    unsigned end = A2[b];
    unsigned go = offA[b];
    for (unsigned i = beg; i < end; ++i) payload[go + i] = stage[i];
  }
}

// ---------------- Encoder EdgeConv: 3-stage MFMA chain, nsplit-way --------
// min-waves hint 4 (not 8): 8 caps VGPR at 32 -> per-iter scratch spills
// (rounds 2-3: ~100 MB HBM traffic). Structure frozen at the R4 optimum;
// 4 structural variants (occupancy, prefetch depth, edges/iter, atomic
// shape) all measured 99-101 us.
__global__ __launch_bounds__(256, 4) void enc_bucket(
    const float4* __restrict__ x, const unsigned* __restrict__ payload,
    const unsigned* __restrict__ start, const float* __restrict__ ab,
    const float* __restrict__ eb1, const float* __restrict__ eb2,
    const h2f16* __restrict__ wpk, float4* __restrict__ mvpart,
    float* __restrict__ cpart, int nsplit) {
  __shared__ float aM0[NB], aM1[NB], aV0[NB], aV1[NB], aC[NB];
  __shared__ float4 xt[NB];
  int k = blockIdx.x, node0 = k * NB, h = blockIdx.y;
  int tid = threadIdx.x, w = tid >> 6, lane = tid & 63;
  int q = lane >> 4, c = lane & 15;
  unsigned s0v = start[k], s1v = start[k + 1];
  unsigned len = s1v - s0v, qlen = (len + (unsigned)nsplit - 1u) / (unsigned)nsplit;
  unsigned lo = s0v + (unsigned)h * qlen;
  unsigned hi = lo + qlen;
  if (hi > s1v) hi = s1v;
  if (tid < NB) {
    int n = node0 + tid;
    aM0[tid] = 0; aM1[tid] = 0; aV0[tid] = 0; aV1[tid] = 0; aC[tid] = 0;
    xt[tid] = x[n < N_NODES ? n : 0];
  }
  __syncthreads();
  float a0 = ab[0], a1 = ab[1], a2 = ab[2], a3 = ab[3];
  float b0 = ab[4], b1 = ab[5], b2 = ab[6], b3 = ab[7];
  const u32x4* a2t = (const u32x4*)(wpk + PK_ENC_A2);
  const u32x4* a1t = (const u32x4*)(wpk + PK_ENC_A1);
  const u32x4* hat = (const u32x4*)(wpk + PK_ENC_HA);
  f16x8 A20 = __builtin_bit_cast(f16x8, a2t[lane]);
  f16x8 A21 = __builtin_bit_cast(f16x8, a2t[64 + lane]);
  f16x8 A10 = __builtin_bit_cast(f16x8, a1t[lane]);
  f16x8 A11 = __builtin_bit_cast(f16x8, a1t[64 + lane]);
  f16x8 HA = __builtin_bit_cast(f16x8, hat[lane]);
  float e1a[4], e1b[4], e2a[4], e2b[4];
#pragma unroll
  for (int r = 0; r < 4; ++r) {
    e1a[r] = eb1[4 * q + r];
    e1b[r] = eb1[16 + 4 * q + r];
    e2a[r] = eb2[4 * q + r];
    e2b[r] = eb2[16 + 4 * q + r];
  }
  unsigned base = lo + (unsigned)w * 32u;
  if (base < hi) {
    unsigned eA = base + (unsigned)c;
    eA = eA < hi ? eA : hi - 1u;
    unsigned eB = base + 16u + (unsigned)c;
    eB = eB < hi ? eB : hi - 1u;
    unsigned pA = payload[eA], pB = payload[eB];
    float4 xjA = x[(int)(pA & 0x1FFFFu)];
    float4 xjB = x[(int)(pB & 0x1FFFFu)];
    f32x4 zf = {0.f, 0.f, 0.f, 0.f};
    for (; base < hi; base += 128u) {
      // prefetch next iteration's payload (harmless clamped re-read at tail)
      unsigned nb = base + 128u;
      unsigned eAn = nb + (unsigned)c;
      eAn = eAn < hi ? eAn : hi - 1u;
      unsigned eBn = nb + 16u + (unsigned)c;
      eBn = eBn < hi ? eBn : hi - 1u;
      unsigned pAn = payload[eAn];
      unsigned pBn = payload[eBn];
      int ltiA = (int)(pA >> 17), ltiB = (int)(pB >> 17);
      float4 xiA = xt[ltiA], xiB = xt[ltiB];
      bool vA = (base + (unsigned)c) < hi;
      bool vB = (base + 16u + (unsigned)c) < hi;
      // features (k-slots 0..7 real for q==0; A1 zero-rows kill the rest)
      u32x4 fuA, fuB;
      fuA[0] = h2u(pk(fmaf(a0, xiA.x, b0), fmaf(a1, xiA.y, b1)));
      fuA[1] = h2u(pk(fmaf(a2, xiA.z, b2), fmaf(a3, xiA.w, b3)));
      fuA[2] = h2u(pk(a0 * (xjA.x - xiA.x), a1 * (xjA.y - xiA.y)));
      fuA[3] = h2u(pk(a2 * (xjA.z - xiA.z), a3 * (xjA.w - xiA.w)));
      fuB[0] = h2u(pk(fmaf(a0, xiB.x, b0), fmaf(a1, xiB.y, b1)));
      fuB[1] = h2u(pk(fmaf(a2, xiB.z, b2), fmaf(a3, xiB.w, b3)));
      fuB[2] = h2u(pk(a0 * (xjB.x - xiB.x), a1 * (xjB.y - xiB.y)));
      fuB[3] = h2u(pk(a2 * (xjB.z - xiB.z), a3 * (xjB.w - xiB.w)));
      // prefetch next x gathers while the MFMA chain runs
      float4 xjAn = x[(int)(pAn & 0x1FFFFu)];
      float4 xjBn = x[(int)(pBn & 0x1FFFFu)];
      f16x8 FA = __builtin_bit_cast(f16x8, fuA);
      f16x8 FB = __builtin_bit_cast(f16x8, fuB);
      // layer1 (K=8 zero-padded)
      f32x4 D10A = mfma16(A10, FA, zf), D11A = mfma16(A11, FA, zf);
      f32x4 D10B = mfma16(A10, FB, zf), D11B = mfma16(A11, FB, zf);
      // bias+relu, pack in tau order -> layer2 B-fragment (no shuffles)
      u32x4 h1A, h1B;
      h1A[0] = h2u(pk(fmaxf(D10A[0] + e1a[0], 0.f), fmaxf(D10A[1] + e1a[1], 0.f)));
      h1A[1] = h2u(pk(fmaxf(D10A[2] + e1a[2], 0.f), fmaxf(D10A[3] + e1a[3], 0.f)));
      h1A[2] = h2u(pk(fmaxf(D11A[0] + e1b[0], 0.f), fmaxf(D11A[1] + e1b[1], 0.f)));
      h1A[3] = h2u(pk(fmaxf(D11A[2] + e1b[2], 0.f), fmaxf(D11A[3] + e1b[3], 0.f)));
      h1B[0] = h2u(pk(fmaxf(D10B[0] + e1a[0], 0.f), fmaxf(D10B[1] + e1a[1], 0.f)));
      h1B[1] = h2u(pk(fmaxf(D10B[2] + e1a[2], 0.f), fmaxf(D10B[3] + e1a[3], 0.f)));
      h1B[2] = h2u(pk(fmaxf(D11B[0] + e1b[0], 0.f), fmaxf(D11B[1] + e1b[1], 0.f)));
      h1B[3] = h2u(pk(fmaxf(D11B[2] + e1b[2], 0.f), fmaxf(D11B[3] + e1b[3], 0.f)));
      f16x8 B2A = __builtin_bit_cast(f16x8, h1A);
      f16x8 B2B = __builtin_bit_cast(f16x8, h1B);
      // layer2 (A tau-permuted to match)
      f32x4 C0A = mfma16(A20, B2A, zf), C1A = mfma16(A21, B2A, zf);
      f32x4 C0B = mfma16(A20, B2B, zf), C1B = mfma16(A21, B2B, zf);
      // bias+relu, pack in tau order -> head B-fragment
      u32x4 g2A, g2B;
      g2A[0] = h2u(pk(fmaxf(C0A[0] + e2a[0], 0.f), fmaxf(C0A[1] + e2a[1], 0.f)));
      g2A[1] = h2u(pk(fmaxf(C0A[2] + e2a[2], 0.f), fmaxf(C0A[3] + e2a[3], 0.f)));
      g2A[2] = h2u(pk(fmaxf(C1A[0] + e2b[0], 0.f), fmaxf(C1A[1] + e2b[1], 0.f)));
      g2A[3] = h2u(pk(fmaxf(C1A[2] + e2b[2], 0.f), fmaxf(C1A[3] + e2b[3], 0.f)));
      g2B[0] = h2u(pk(fmaxf(C0B[0] + e2a[0], 0.f), fmaxf(C0B[1] + e2a[1], 0.f)));
      g2B[1] = h2u(pk(fmaxf(C0B[2] + e2a[2], 0.f), fmaxf(C0B[3] + e2a[3], 0.f)));
      g2B[2] = h2u(pk(fmaxf(C1B[0] + e2b[0], 0.f), fmaxf(C1B[1] + e2b[1], 0.f)));
      g2B[3] = h2u(pk(fmaxf(C1B[2] + e2b[2], 0.f), fmaxf(C1B[3] + e2b[3], 0.f)));
      // head MFMA: D2[out=r, edge=c] lands in q==0 lanes, regs 0..3
      f32x4 D2A = mfma16(HA, __builtin_bit_cast(f16x8, g2A), zf);
      f32x4 D2B = mfma16(HA, __builtin_bit_cast(f16x8, g2B), zf);
      if (lane < 16) {
        if (vA) {
          atomicAdd(&aM0[ltiA], D2A[0]);
          atomicAdd(&aM1[ltiA], D2A[1]);
          atomicAdd(&aV0[ltiA], D2A[2]);
          atomicAdd(&aV1[ltiA], D2A[3]);
          atomicAdd(&aC[ltiA], 1.0f);
        }
        if (vB) {
          atomicAdd(&aM0[ltiB], D2B[0]);
          atomicAdd(&aM1[ltiB], D2B[1]);
          atomicAdd(&aV0[ltiB], D2B[2]);
          atomicAdd(&aV1[ltiB], D2B[3]);
          atomicAdd(&aC[ltiB], 1.0f);
        }
      }
      pA = pAn; pB = pBn; xjA = xjAn; xjB = xjBn;
    }
  }
  __syncthreads();
  // plain-store partial slice (empty-range blocks store zeros; no memset,
  // no global atomics -> no line-granular RMW traffic)
  if (tid < NB) {
    int n = node0 + tid;
    if (n < N_NODES) {
      mvpart[(size_t)h * N_NODES + n] =
          make_float4(aM0[tid], aM1[tid], aV0[tid], aV1[tid]);
      cpart[(size_t)h * N_NODES + n] = aC[tid];
    }
  }
}

// ---------------- reduce partials + mean + bias + reparameterize ----------
__global__ __launch_bounds__(256) void node_mid(
    const float4* __restrict__ mvpart, const float* __restrict__ cpart,
    const float* __restrict__ eps2, const float* __restrict__ mbias,
    const float* __restrict__ vbias, float* __restrict__ z,
    float* __restrict__ cntC, float2* __restrict__ muOut,
    float2* __restrict__ lvOut, int nsplit) {
  int n = blockIdx.x * 256 + threadIdx.x;
  if (n >= N_NODES) return;
  float m0 = 0, m1 = 0, v0 = 0, v1 = 0, cc = 0;
  for (int h = 0; h < nsplit; ++h) {
    float4 t = mvpart[(size_t)h * N_NODES + n];
    m0 += t.x; m1 += t.y; v0 += t.z; v1 += t.w;
    cc += cpart[(size_t)h * N_NODES + n];
  }
  float inv = 1.0f / fmaxf(cc, 1.0f);
  float mu0 = fmaf(m0, inv, mbias[0]);
  float mu1 = fmaf(m1, inv, mbias[1]);
  float lv0 = fmaf(v0, inv, vbias[0]);
  float lv1 = fmaf(v1, inv, vbias[1]);
  cntC[n] = cc;
  muOut[n] = make_float2(mu0, mu1);
  lvOut[n] = make_float2(lv0, lv1);
  z[2 * n + 0] = fmaf(eps2[2 * n + 0], expf(0.5f * lv0), mu0);
  z[2 * n + 1] = fmaf(eps2[2 * n + 1], expf(0.5f * lv1), mu1);
}

// ---------------- Decoder EdgeConv: 3-stage MFMA chain, nsplit-way --------
__global__ __launch_bounds__(256, 4) void dec_bucket(
    const float2* __restrict__ z, const unsigned* __restrict__ payload,
    const unsigned* __restrict__ start, const float* __restrict__ db1,
    const float* __restrict__ db2, const h2f16* __restrict__ wpk,
    float4* __restrict__ opart, int nsplit) {
  __shared__ float aO0[NB], aO1[NB], aO2[NB], aO3[NB];
  __shared__ float2 zt[NB];
  int k = blockIdx.x, node0 = k * NB, h = blockIdx.y;
  int tid = threadIdx.x, w = tid >> 6, lane = tid & 63;
  int q = lane >> 4, c = lane & 15;
  unsigned s0v = start[k], s1v = start[k + 1];
  unsigned len = s1v - s0v, qlen = (len + (unsigned)nsplit - 1u) / (unsigned)nsplit;
  unsigned lo = s0v + (unsigned)h * qlen;
  unsigned hi = lo + qlen;
  if (hi > s1v) hi = s1v;
  if (tid < NB) {
    int n = node0 + tid;
    aO0[tid] = 0; aO1[tid] = 0; aO2[tid] = 0; aO3[tid] = 0;
    zt[tid] = z[n < N_NODES ? n : 0];
  }
  __syncthreads();
  const u32x4* a2t = (const u32x4*)(wpk + PK_DEC_A2);
  const u32x4* a1t = (const u32x4*)(wpk + PK_DEC_A1);
  const u32x4* hat = (const u32x4*)(wpk + PK_DEC_HA);
  f16x8 A20 = __builtin_bit_cast(f16x8, a2t[lane]);
  f16x8 A21 = __builtin_bit_cast(f16x8, a2t[64 + lane]);
  f16x8 A10 = __builtin_bit_cast(f16x8, a1t[lane]);
  f16x8 A11 = __builtin_bit_cast(f16x8, a1t[64 + lane]);
  f16x8 HA = __builtin_bit_cast(f16x8, hat[lane]);
  float e1a[4], e1b[4], e2a[4], e2b[4];
#pragma unroll
  for (int r = 0; r < 4; ++r) {
    e1a[r] = db1[4 * q + r];
    e1b[r] = db1[16 + 4 * q + r];
    e2a[r] = db2[4 * q + r];
    e2b[r] = db2[16 + 4 * q + r];
  }
  unsigned base = lo + (unsigned)w * 32u;
  if (base < hi) {
    unsigned eA = base + (unsigned)c;
    eA = eA < hi ? eA : hi - 1u;
    unsigned eB = base + 16u + (unsigned)c;
    eB = eB < hi ? eB : hi - 1u;
    unsigned pA = payload[eA], pB = payload[eB];
    float2 zjA = z[(int)(pA & 0x1FFFFu)];
    float2 zjB = z[(int)(pB & 0x1FFFFu)];
    f32x4 zf = {0.f, 0.f, 0.f, 0.f};
    for (; base < hi; base += 128u) {
      unsigned nb = base + 128u;
      unsigned eAn = nb + (unsigned)c;
      eAn = eAn < hi ? eAn : hi - 1u;
      unsigned eBn = nb + 16u + (unsigned)c;
      eBn = eBn < hi ? eBn : hi - 1u;
      unsigned pAn = payload[eAn];
      unsigned pBn = payload[eBn];
      int ltiA = (int)(pA >> 17), ltiB = (int)(pB >> 17);
      float2 ziA = zt[ltiA], ziB = zt[ltiB];
      bool vA = (base + (unsigned)c) < hi;
      bool vB = (base + 16u + (unsigned)c) < hi;
      // features: 4 real k-slots; upper slots junk (A1 zero-rows kill them)
      u32x4 fuA, fuB;
      fuA[0] = h2u(pk(ziA.x, ziA.y));
      fuA[1] = h2u(pk(zjA.x - ziA.x, zjA.y - ziA.y));
      fuA[2] = fuA[0];
      fuA[3] = fuA[1];
      fuB[0] = h2u(pk(ziB.x, ziB.y));
      fuB[1] = h2u(pk(zjB.x - ziB.x, zjB.y - ziB.y));
      fuB[2] = fuB[0];
      fuB[3] = fuB[1];
      float2 zjAn = z[(int)(pAn & 0x1FFFFu)];
      float2 zjBn = z[(int)(pBn & 0x1FFFFu)];
      f16x8 FA = __builtin_bit_cast(f16x8, fuA);
      f16x8 FB = __builtin_bit_cast(f16x8, fuB);
      f32x4 D10A = mfma16(A10, FA, zf), D11A = mfma16(A11, FA, zf);
      f32x4 D10B = mfma16(A10, FB, zf), D11B = mfma16(A11, FB, zf);
      u32x4 h1A, h1B;
      h1A[0] = h2u(pk(fmaxf(D10A[0] + e1a[0], 0.f), fmaxf(D10A[1] + e1a[1], 0.f)));
      h1A[1] = h2u(pk(fmaxf(D10A[2] + e1a[2], 0.f), fmaxf(D10A[3] + e1a[3], 0.f)));
      h1A[2] = h2u(pk(fmaxf(D11A[0] + e1b[0], 0.f), fmaxf(D11A[1] + e1b[1], 0.f)));
      h1A[3] = h2u(pk(fmaxf(D11A[2] + e1b[2], 0.f), fmaxf(D11A[3] + e1b[3], 0.f)));
      h1B[0] = h2u(pk(fmaxf(D10B[0] + e1a[0], 0.f), fmaxf(D10B[1] + e1a[1], 0.f)));
      h1B[1] = h2u(pk(fmaxf(D10B[2] + e1a[2], 0.f), fmaxf(D10B[3] + e1a[3], 0.f)));
      h1B[2] = h2u(pk(fmaxf(D11B[0] + e1b[0], 0.f), fmaxf(D11B[1] + e1b[1], 0.f)));
      h1B[3] = h2u(pk(fmaxf(D11B[2] + e1b[2], 0.f), fmaxf(D11B[3] + e1b[3], 0.f)));
      f16x8 B2A = __builtin_bit_cast(f16x8, h1A);
      f16x8 B2B = __builtin_bit_cast(f16x8, h1B);
      f32x4 C0A = mfma16(A20, B2A, zf), C1A = mfma16(A21, B2A, zf);
      f32x4 C0B = mfma16(A20, B2B, zf), C1B = mfma16(A21, B2B, zf);
      u32x4 g2A, g2B;
      g2A[0] = h2u(pk(fmaxf(C0A[0] + e2a[0], 0.f), fmaxf(C0A[1] + e2a[1], 0.f)));
      g2A[1] = h2u(pk(fmaxf(C0A[2] + e2a[2], 0.f), fmaxf(C0A[3] + e2a[3], 0.f)));
      g2A[2] = h2u(pk(fmaxf(C1A[0] + e2b[0], 0.f), fmaxf(C1A[1] + e2b[1], 0.f)));
      g2A[3] = h2u(pk(fmaxf(C1A[2] + e2b[2], 0.f), fmaxf(C1A[3] + e2b[3], 0.f)));
      g2B[0] = h2u(pk(fmaxf(C0B[0] + e2a[0], 0.f), fmaxf(C0B[1] + e2a[1], 0.f)));
      g2B[1] = h2u(pk(fmaxf(C0B[2] + e2a[2], 0.f), fmaxf(C0B[3] + e2a[3], 0.f)));
      g2B[2] = h2u(pk(fmaxf(C1B[0] + e2b[0], 0.f), fmaxf(C1B[1] + e2b[1], 0.f)));
      g2B[3] = h2u(pk(fmaxf(C1B[2] + e2b[2], 0.f), fmaxf(C1B[3] + e2b[3], 0.f)));
      f32x4 D2A = mfma16(HA, __builtin_bit_cast(f16x8, g2A), zf);
      f32x4 D2B = mfma16(HA, __builtin_bit_cast(f16x8, g2B), zf);
      if (lane < 16) {
        if (vA) {
          atomicAdd(&aO0[ltiA], D2A[0]);
          atomicAdd(&aO1[ltiA], D2A[1]);
          atomicAdd(&aO2[ltiA], D2A[2]);
          atomicAdd(&aO3[ltiA], D2A[3]);
        }
        if (vB) {
          atomicAdd(&aO0[ltiB], D2B[0]);
          atomicAdd(&aO1[ltiB], D2B[1]);
          atomicAdd(&aO2[ltiB], D2B[2]);
          atomicAdd(&aO3[ltiB], D2B[3]);
        }
      }
      pA = pAn; pB = pBn; zjA = zjAn; zjB = zjBn;
    }
  }
  __syncthreads();
  if (tid < NB) {
    int n = node0 + tid;
    if (n < N_NODES)
      opart[(size_t)h * N_NODES + n] =
          make_float4(aO0[tid], aO1[tid], aO2[tid], aO3[tid]);
  }
}

__global__ __launch_bounds__(256) void node_final(
    const float4* __restrict__ opart, const float* __restrict__ cntC,
    const float* __restrict__ db3, float4* __restrict__ outp, int nsplit) {
  int n = blockIdx.x * 256 + threadIdx.x;
  if (n >= N_NODES) return;
  float o0 = 0, o1 = 0, o2 = 0, o3 = 0;
  for (int h = 0; h < nsplit; ++h) {
    float4 t = opart[(size_t)h * N_NODES + n];
    o0 += t.x; o1 += t.y; o2 += t.z; o3 += t.w;
  }
  float cc = cntC[n];
  if (cc > 0.0f) {
    float inv = 1.0f / cc;
    outp[n] = make_float4(fmaf(o0, inv, db3[0]), fmaf(o1, inv, db3[1]),
                          fmaf(o2, inv, db3[2]), fmaf(o3, inv, db3[3]));
  } else {
    outp[n] = make_float4(0.f, 0.f, 0.f, 0.f);
  }
}

// ---------------- fallback (device-scope atomics, fp32, round-1 proven) ----
__global__ __launch_bounds__(256) void enc_edge_fb(
    const float4* __restrict__ x, const int* __restrict__ esrc,
    const int* __restrict__ etgt, const float* __restrict__ ab,
    const float* __restrict__ eW1, const float* __restrict__ eb1,
    const float* __restrict__ eW2, const float* __restrict__ eb2,
    const float* __restrict__ mW, const float* __restrict__ vW,
    float* __restrict__ msum, float* __restrict__ vsum,
    float* __restrict__ cnt) {
  int e = blockIdx.x * 256 + threadIdx.x;
  if (e >= N_EDGES) return;
  int si = esrc[e], ti = etgt[e];
  float4 xi = x[ti];
  float4 xj = x[si];
  float a0 = ab[0], a1 = ab[1], a2 = ab[2], a3 = ab[3];
  float b0 = ab[4], b1 = ab[5], b2 = ab[6], b3 = ab[7];
  float feat[8];
  feat[0] = fmaf(a0, xi.x, b0);
  feat[1] = fmaf(a1, xi.y, b1);
  feat[2] = fmaf(a2, xi.z, b2);
  feat[3] = fmaf(a3, xi.w, b3);
  feat[4] = a0 * (xj.x - xi.x);
  feat[5] = a1 * (xj.y - xi.y);
  feat[6] = a2 * (xj.z - xi.z);
  feat[7] = a3 * (xj.w - xi.w);
  float h1[32];
#pragma unroll 8
  for (int j = 0; j < 32; ++j) {
    float acc = eb1[j];
#pragma unroll
    for (int kk = 0; kk < 8; ++kk) acc = fmaf(feat[kk], eW1[kk * 32 + j], acc);
    h1[j] = fmaxf(acc, 0.0f);
  }
  float m0 = 0, m1 = 0, v0 = 0, v1 = 0;
#pragma unroll 4
  for (int j = 0; j < 32; ++j) {
    float acc = eb2[j];
#pragma unroll
    for (int kk = 0; kk < 32; ++kk) acc = fmaf(h1[kk], eW2[kk * 32 + j], acc);
    float h2 = fmaxf(acc, 0.0f);
    m0 = fmaf(h2, mW[j * 2 + 0], m0);
    m1 = fmaf(h2, mW[j * 2 + 1], m1);
    v0 = fmaf(h2, vW[j * 2 + 0], v0);
    v1 = fmaf(h2, vW[j * 2 + 1], v1);
  }
  atomAddF(&msum[ti * 2 + 0], m0);
  atomAddF(&msum[ti * 2 + 1], m1);
  atomAddF(&vsum[ti * 2 + 0], v0);
  atomAddF(&vsum[ti * 2 + 1], v1);
  atomAddF(&cnt[ti], 1.0f);
}

__global__ __launch_bounds__(256) void dec_edge_fb(
    const float2* __restrict__ z, const int* __restrict__ esrc,
    const int* __restrict__ etgt, const float* __restrict__ dW1,
    const float* __restrict__ db1, const float* __restrict__ dW2,
    const float* __restrict__ db2, const float* __restrict__ dW3,
    const float* __restrict__ db3, float* __restrict__ osum) {
  int e = blockIdx.x * 256 + threadIdx.x;
  if (e >= N_EDGES) return;
  int si = esrc[e], ti = etgt[e];
  float2 zi = z[ti], zj = z[si];
  float f0 = zi.x, f1 = zi.y, f2 = zj.x - zi.x, f3 = zj.y - zi.y;
  float h1[32];
#pragma unroll 8
  for (int j = 0; j < 32; ++j) {
    float acc = db1[j];
    acc = fmaf(f0, dW1[0 * 32 + j], acc);
    acc = fmaf(f1, dW1[1 * 32 + j], acc);
    acc = fmaf(f2, dW1[2 * 32 + j], acc);
    acc = fmaf(f3, dW1[3 * 32 + j], acc);
    h1[j] = fmaxf(acc, 0.0f);
  }
  float o0 = db3[0], o1 = db3[1], o2 = db3[2], o3 = db3[3];
#pragma unroll 4
  for (int j = 0; j < 32; ++j) {
    float acc = db2[j];
#pragma unroll
    for (int kk = 0; kk < 32; ++kk) acc = fmaf(h1[kk], dW2[kk * 32 + j], acc);
    float h2 = fmaxf(acc, 0.0f);
    o0 = fmaf(h2, dW3[j * 4 + 0], o0);
    o1 = fmaf(h2, dW3[j * 4 + 1], o1);
    o2 = fmaf(h2, dW3[j * 4 + 2], o2);
    o3 = fmaf(h2, dW3[j * 4 + 3], o3);
  }
  atomAddF(&osum[4 * ti + 0], o0);
  atomAddF(&osum[4 * ti + 1], o1);
  atomAddF(&osum[4 * ti + 2], o2);
  atomAddF(&osum[4 * ti + 3], o3);
}

__global__ __launch_bounds__(256) void node_mid_fb(
    float* __restrict__ msum, float* __restrict__ vsum,
    const float* __restrict__ cnt, const float* __restrict__ eps2,
    const float* __restrict__ mb, const float* __restrict__ vb,
    float* __restrict__ z) {
  int n = blockIdx.x * 256 + threadIdx.x;
  if (n >= N_NODES) return;
  float inv = 1.0f / fmaxf(cnt[n], 1.0f);
  float mu0 = fmaf(msum[2 * n + 0], inv, mb[0]);
  float mu1 = fmaf(msum[2 * n + 1], inv, mb[1]);
  float lv0 = fmaf(vsum[2 * n + 0], inv, vb[0]);
  float lv1 = fmaf(vsum[2 * n + 1], inv, vb[1]);
  msum[2 * n + 0] = mu0;
  msum[2 * n + 1] = mu1;
  vsum[2 * n + 0] = lv0;
  vsum[2 * n + 1] = lv1;
  z[2 * n + 0] = fmaf(eps2[2 * n + 0], expf(0.5f * lv0), mu0);
  z[2 * n + 1] = fmaf(eps2[2 * n + 1], expf(0.5f * lv1), mu1);
}

__global__ __launch_bounds__(256) void node_final_fb(
    float* __restrict__ osum, const float* __restrict__ cnt) {
  int n = blockIdx.x * 256 + threadIdx.x;
  if (n >= N_NODES) return;
  float inv = 1.0f / fmaxf(cnt[n], 1.0f);
  float4* o4 = (float4*)osum;
  float4 v = o4[n];
  v.x *= inv; v.y *= inv; v.z *= inv; v.w *= inv;
  o4[n] = v;
}

extern "C" void kernel_launch(void* const* d_in, const int* in_sizes, int n_in,
                              void* d_out, int out_size, void* d_ws,
                              size_t ws_size, hipStream_t stream) {
  const float* x = (const float*)d_in[0];
  const int* ei = (const int*)d_in[1];
  const float* eps = (const float*)d_in[2];
  const float* bng = (const float*)d_in[3];
  const float* bnb = (const float*)d_in[4];
  const float* eW1 = (const float*)d_in[5];
  const float* eb1 = (const float*)d_in[6];
  const float* eW2 = (const float*)d_in[7];
  const float* eb2 = (const float*)d_in[8];
  const float* mW = (const float*)d_in[9];
  const float* mb = (const float*)d_in[10];
  const float* vW = (const float*)d_in[11];
  const float* vb = (const float*)d_in[12];
  const float* dW1 = (const float*)d_in[13];
  const float* db1 = (const float*)d_in[14];
  const float* dW2 = (const float*)d_in[15];
  const float* db2 = (const float*)d_in[16];
  const float* dW3 = (const float*)d_in[17];
  const float* db3 = (const float*)d_in[18];

  float* out = (float*)d_out;  // [N,4] out | [N,2] mu | [N,2] logvar
  const size_t N = N_NODES;

  const size_t sortBytes =
      ((size_t)(NBUCK + 1) + (size_t)NSLICE * NBUCK + N_EDGES + PK_TOTAL) *
      sizeof(unsigned);
  // floats: 16 hdr + z 2N + cntC N + mvpart 4sN + cpart sN + opart 4sN
  auto reqFor = [&](int s) {
    return (16 + 3 * N + 9 * (size_t)s * N) * sizeof(float) + sortBytes;
  };
  int ns = 0;
  if (ws_size >= reqFor(4)) ns = 4;
  else if (ws_size >= reqFor(2)) ns = 2;
  else if (ws_size >= reqFor(1)) ns = 1;

  float* wsf = (float*)d_ws;
  float* bns = wsf;                          // 8
  float* ab = wsf + 8;                       // 8
  float* z = wsf + 16;                       // 2N
  float* cntC = z + 2 * N;                   // N
  float4* mvpart = (float4*)(cntC + N);      // ns*N float4
  float* cpart = (float*)(mvpart + (size_t)ns * N);  // ns*N
  float4* opart = (float4*)(cpart + (size_t)ns * N); // ns*N float4
  unsigned* start = (unsigned*)((float*)opart + 4 * (size_t)ns * N);  // NBUCK+1
  unsigned* hist = start + (NBUCK + 1);                  // NSLICE*NBUCK
  unsigned* payload = hist + (size_t)NSLICE * NBUCK;     // N_EDGES
  h2f16* wpk = (h2f16*)(payload + N_EDGES);              // PK_TOTAL

  if (ns > 0) {
    (void)hipMemsetAsync(bns, 0, 8 * sizeof(float), stream);
    // tot accumulator lives in the payload buffer until edge_place overwrites
    (void)hipMemsetAsync(payload, 0, NBUCK * sizeof(unsigned), stream);
    pack_weights<<<1, 256, 0, stream>>>(eW1, eW2, mW, vW, dW1, dW2, dW3, wpk);
    bn_reduce<<<256, 256, 0, stream>>>((const float4*)x, bns);
    bn_final<<<1, 64, 0, stream>>>(bns, bng, bnb, ab);
    edge_hist<<<NSLICE, 256, 0, stream>>>(ei + N_EDGES, hist, payload);
    bucket_start<<<1, 1024, 0, stream>>>(payload, start);
    bucket_bases<<<(NBUCK + 3) / 4, 256, 0, stream>>>(hist, start);
    edge_place<<<NSLICE, 256, 0, stream>>>(ei, ei + N_EDGES, hist, start,
                                           payload);
    dim3 gE(NBUCK, ns);
    enc_bucket<<<gE, 256, 0, stream>>>((const float4*)x, payload, start, ab,
                                       eb1, eb2, wpk, mvpart, cpart, ns);
    node_mid<<<NBLK_NODE, 256, 0, stream>>>(mvpart, cpart, eps, mb, vb, z,
                                            cntC, (float2*)(out + 4 * N),
                                            (float2*)(out + 6 * N), ns);
    dec_bucket<<<gE, 256, 0, stream>>>((const float2*)z, payload, start, db1,
                                       db2, wpk, opart, ns);
    node_final<<<NBLK_NODE, 256, 0, stream>>>(opart, cntC, db3, (float4*)out,
                                              ns);
  } else {
    // fallback: device-scope atomics (round-1 proven path)
    float* cntf = wsf + 16;       // N
    float* zf = wsf + 16 + N;     // 2N
    float* msum = out + 4 * N;
    float* vsum = out + 6 * N;
    (void)hipMemsetAsync(d_out, 0, 8 * N * sizeof(float), stream);
    (void)hipMemsetAsync(d_ws, 0, (16 + N) * sizeof(float), stream);
    bn_reduce<<<256, 256, 0, stream>>>((const float4*)x, bns);
    bn_final<<<1, 64, 0, stream>>>(bns, bng, bnb, ab);
    enc_edge_fb<<<NBLK_EDGE, 256, 0, stream>>>((const float4*)x, ei,
                                               ei + N_EDGES, ab, eW1, eb1, eW2,
                                               eb2, mW, vW, msum, vsum, cntf);
    node_mid_fb<<<NBLK_NODE, 256, 0, stream>>>(msum, vsum, cntf, eps, mb, vb,
                                               zf);
    dec_edge_fb<<<NBLK_EDGE, 256, 0, stream>>>((const float2*)zf, ei,
                                               ei + N_EDGES, dW1, db1, dW2, db2,
                                               dW3, db3, out);
    node_final_fb<<<NBLK_NODE, 256, 0, stream>>>(out, cntf);
  }
}

// Round 8
// 331.495 us; speedup vs baseline: 1.1075x; 1.0723x over previous
//
#include <hip/hip_runtime.h>
#include <math.h>

#define N_NODES 100000
#define N_EDGES 3200000
#define NBLK_EDGE ((N_EDGES + 255) / 256)
#define NBLK_NODE ((N_NODES + 255) / 256)

#define NB 64                                // nodes per bucket
#define NBUCK ((N_NODES + NB - 1) / NB)      // 1563
#define NSLICE 256
#define SLICE (N_EDGES / NSLICE)             // 12500 exact

typedef _Float16 h2f16 __attribute__((ext_vector_type(2)));
typedef __fp16 f16x8 __attribute__((ext_vector_type(8)));   // MFMA operand type
typedef float f32x4 __attribute__((ext_vector_type(4)));
typedef unsigned u32x4 __attribute__((ext_vector_type(4)));

// packed-weight table offsets (h2f16 units)
// All A-fragments for 16x16x32 f16 MFMA: lane(q,c) holds A[row=c, kslot=8q+j].
// Layer2 A is k-permuted by tau(8q+j) = j<4 ? 4q+j : 16+4q+(j-4) so the
// layer1 D-fragment packs in-lane into layer2's B; head A likewise so layer2's
// D packs in-lane into the head's B. tau is a bijection on [0,32).
#define PK_ENC_A2 0     // 2 tiles x 64 lanes x 4 pairs (W2^T, tau-permuted k)
#define PK_DEC_A2 512
#define PK_ENC_A1 1024  // 2 tiles x 64 lanes x 4 pairs (W1^T, natural k, rows>=8 zero)
#define PK_DEC_A1 1536
#define PK_ENC_HA 2048  // 64 lanes x 4 pairs (head weights, tau-permuted k, rows>=4 zero)
#define PK_DEC_HA 2304
#define PK_TOTAL 2560

__device__ __forceinline__ h2f16 mkh2(float a, float b) {
  h2f16 h;
  h.x = (_Float16)a;
  h.y = (_Float16)b;
  return h;
}
__device__ __forceinline__ h2f16 pk(float a, float b) {
  auto r = __builtin_amdgcn_cvt_pkrtz(a, b);  // v_cvt_pkrtz_f16_f32
  return __builtin_bit_cast(h2f16, r);
}
__device__ __forceinline__ unsigned h2u(h2f16 h) {
  return __builtin_bit_cast(unsigned, h);
}
__device__ __forceinline__ f32x4 mfma16(f16x8 a, f16x8 b, f32x4 c) {
  return __builtin_amdgcn_mfma_f32_16x16x32_f16(a, b, c, 0, 0, 0);
}
__device__ __forceinline__ void atomAddF(float* p, float v) {
  unsafeAtomicAdd(p, v);
}

// ---------------- device helper: pack weights (called from prep blk 0) ----
__device__ void pack_weights_body(
    int t, const float* __restrict__ eW1, const float* __restrict__ eW2,
    const float* __restrict__ mW, const float* __restrict__ vW,
    const float* __restrict__ dW1, const float* __restrict__ dW2,
    const float* __restrict__ dW3, h2f16* __restrict__ wpk) {
  // layer2 A-fragments, tau-permuted k
  for (int i = t; i < 512; i += 256) {
    int tl = i >> 8, rest = i & 255, lane = rest >> 2, p = rest & 3;
    int q = lane >> 4, c = lane & 15;
    int out = 16 * tl + c;
    int k0 = (p < 2) ? (4 * q + 2 * p) : (16 + 4 * q + 2 * (p - 2));  // tau
    wpk[PK_ENC_A2 + i] = mkh2(eW2[k0 * 32 + out], eW2[(k0 + 1) * 32 + out]);
    wpk[PK_DEC_A2 + i] = mkh2(dW2[k0 * 32 + out], dW2[(k0 + 1) * 32 + out]);
  }
  // layer1 A-fragments, natural k (enc: k<8 real, dec: k<4 real, rest zero)
  for (int i = t; i < 512; i += 256) {
    int tl = i >> 8, rest = i & 255, lane = rest >> 2, p = rest & 3;
    int q = lane >> 4, c = lane & 15;
    int out = 16 * tl + c;
    int k0 = 8 * q + 2 * p;
    float w0e = (k0 < 8) ? eW1[k0 * 32 + out] : 0.0f;
    float w1e = (k0 + 1 < 8) ? eW1[(k0 + 1) * 32 + out] : 0.0f;
    float w0d = (k0 < 4) ? dW1[k0 * 32 + out] : 0.0f;
    float w1d = (k0 + 1 < 4) ? dW1[(k0 + 1) * 32 + out] : 0.0f;
    wpk[PK_ENC_A1 + i] = mkh2(w0e, w1e);
    wpk[PK_DEC_A1 + i] = mkh2(w0d, w1d);
  }
  // head A-fragments, tau-permuted k, out-channel = row c (rows>=4 zero)
  for (int i = t; i < 256; i += 256) {
    int lane = i >> 2, p = i & 3;
    int q = lane >> 4, c = lane & 15;
    int d0 = (p < 2) ? (4 * q + 2 * p) : (16 + 4 * q + 2 * (p - 2));  // tau
    int d1 = d0 + 1;
    float e0 = 0.f, e1 = 0.f, g0 = 0.f, g1 = 0.f;
    if (c < 4) {
      e0 = (c < 2) ? mW[d0 * 2 + c] : vW[d0 * 2 + (c - 2)];
      e1 = (c < 2) ? mW[d1 * 2 + c] : vW[d1 * 2 + (c - 2)];
      g0 = dW3[d0 * 4 + c];
      g1 = dW3[d1 * 4 + c];
    }
    wpk[PK_ENC_HA + i] = mkh2(e0, e1);
    wpk[PK_DEC_HA + i] = mkh2(g0, g1);
  }
}

// ---------------- fused: edge histogram + BN partials + weight pack -------
// grid NSLICE(=256) x 256. Block b: histogram of slice b (+ global tot),
// BN partial sums over node stripe b, block 0 also packs weights.
__global__ __launch_bounds__(256) void prep(
    const int* __restrict__ tgt, const float4* __restrict__ x,
    const float* __restrict__ eW1, const float* __restrict__ eW2,
    const float* __restrict__ mW, const float* __restrict__ vW,
    const float* __restrict__ dW1, const float* __restrict__ dW2,
    const float* __restrict__ dW3, unsigned* __restrict__ hist,
    unsigned* __restrict__ tot, float* __restrict__ bns,
    h2f16* __restrict__ wpk) {
  if (blockIdx.x == 0)
    pack_weights_body(threadIdx.x, eW1, eW2, mW, vW, dW1, dW2, dW3, wpk);
  // --- histogram (edge_hist body) ---
  __shared__ unsigned h[NBUCK];
  for (int i = threadIdx.x; i < NBUCK; i += 256) h[i] = 0;
  __syncthreads();
  int e0 = blockIdx.x * SLICE;
  for (int i = threadIdx.x; i < SLICE; i += 256)
    atomicAdd(&h[((unsigned)tgt[e0 + i]) >> 6], 1u);
  __syncthreads();
  for (int i = threadIdx.x; i < NBUCK; i += 256) {
    unsigned hv = h[i];
    hist[(size_t)blockIdx.x * NBUCK + i] = hv;
    if (hv) atomicAdd(&tot[i], hv);
  }
  // --- BN partials (bn_reduce body, grid-stride over nodes) ---
  float s0 = 0, s1 = 0, s2 = 0, s3 = 0, q0 = 0, q1 = 0, q2 = 0, q3 = 0;
  for (int i = blockIdx.x * blockDim.x + threadIdx.x; i < N_NODES;
       i += gridDim.x * blockDim.x) {
    float4 v = x[i];
    s0 += v.x; s1 += v.y; s2 += v.z; s3 += v.w;
    q0 += v.x * v.x; q1 += v.y * v.y; q2 += v.z * v.z; q3 += v.w * v.w;
  }
#pragma unroll
  for (int o = 32; o; o >>= 1) {
    s0 += __shfl_down(s0, o); s1 += __shfl_down(s1, o);
    s2 += __shfl_down(s2, o); s3 += __shfl_down(s3, o);
    q0 += __shfl_down(q0, o); q1 += __shfl_down(q1, o);
    q2 += __shfl_down(q2, o); q3 += __shfl_down(q3, o);
  }
  __shared__ float red[4][8];
  int w = threadIdx.x >> 6;
  if ((threadIdx.x & 63) == 0) {
    red[w][0] = s0; red[w][1] = s1; red[w][2] = s2; red[w][3] = s3;
    red[w][4] = q0; red[w][5] = q1; red[w][6] = q2; red[w][7] = q3;
  }
  __syncthreads();
  if (threadIdx.x < 8) {
    float acc = red[0][threadIdx.x] + red[1][threadIdx.x] +
                red[2][threadIdx.x] + red[3][threadIdx.x];
    atomicAdd(&bns[threadIdx.x], acc);
  }
}

// ---------------- fused: BN finalize + bucket prefix scan -----------------
// 3-level scan (wave shfl + cross-wave), 2 barriers; threads 0-3 also
// finalize the BN affine constants (bns complete after prep).
__global__ __launch_bounds__(1024) void scan_init(
    const unsigned* __restrict__ tot, unsigned* __restrict__ start,
    const float* __restrict__ bns, const float* __restrict__ gamma,
    const float* __restrict__ beta, float* __restrict__ ab) {
  __shared__ unsigned wsum[16];
  int tid = threadIdx.x, lane = tid & 63, wid = tid >> 6;
  if (tid < 4) {
    float mean = bns[tid] * (1.0f / N_NODES);
    float var = bns[4 + tid] * (1.0f / N_NODES) - mean * mean;
    float a = gamma[tid] * rsqrtf(var + 1e-5f);
    ab[tid] = a;
    ab[4 + tid] = beta[tid] - mean * a;  // xn = a*x + b
  }
  int k0 = 2 * tid;
  unsigned v0 = (k0 < NBUCK) ? tot[k0] : 0u;
  unsigned v1 = (k0 + 1 < NBUCK) ? tot[k0 + 1] : 0u;
  unsigned s = v0 + v1, incl = s;
#pragma unroll
  for (int off = 1; off < 64; off <<= 1) {
    unsigned t = __shfl_up(incl, off);
    incl += (lane >= off) ? t : 0u;
  }
  if (lane == 63) wsum[wid] = incl;
  __syncthreads();
  if (tid == 0) {
    unsigned a = 0;
#pragma unroll
    for (int w2 = 0; w2 < 16; ++w2) {
      unsigned t = wsum[w2];
      wsum[w2] = a;
      a += t;
    }
  }
  __syncthreads();
  unsigned excl0 = wsum[wid] + incl - s;
  if (k0 <= NBUCK) start[k0] = excl0;
  if (k0 + 1 <= NBUCK) start[k0 + 1] = excl0 + v0;
}

__global__ __launch_bounds__(256) void bucket_bases(unsigned* __restrict__ hist,
                                                    const unsigned* __restrict__ start) {
  int wv = threadIdx.x >> 6, lane = threadIdx.x & 63;
  int k = blockIdx.x * 4 + wv;
  if (k >= NBUCK) return;
  unsigned v0 = hist[(size_t)(4 * lane + 0) * NBUCK + k];
  unsigned v1 = hist[(size_t)(4 * lane + 1) * NBUCK + k];
  unsigned v2 = hist[(size_t)(4 * lane + 2) * NBUCK + k];
  unsigned v3 = hist[(size_t)(4 * lane + 3) * NBUCK + k];
  unsigned p1 = v0, p2 = v0 + v1, p3 = v0 + v1 + v2;
  unsigned s = p3 + v3;
  unsigned incl = s;
#pragma unroll
  for (int off = 1; off < 64; off <<= 1) {
    unsigned t = __shfl_up(incl, off);
    incl += (lane >= off) ? t : 0u;
  }
  unsigned base = start[k] + (incl - s);
  hist[(size_t)(4 * lane + 0) * NBUCK + k] = base;
  hist[(size_t)(4 * lane + 1) * NBUCK + k] = base + p1;
  hist[(size_t)(4 * lane + 2) * NBUCK + k] = base + p2;
  hist[(size_t)(4 * lane + 3) * NBUCK + k] = base + p3;
}

__global__ __launch_bounds__(256) void edge_place(
    const int* __restrict__ src, const int* __restrict__ tgt,
    const unsigned* __restrict__ hist, const unsigned* __restrict__ start,
    unsigned* __restrict__ payload) {
  __shared__ unsigned stage[SLICE];
  __shared__ unsigned offA[NBUCK];
  __shared__ unsigned A2[NBUCK];
  __shared__ unsigned tsum[4];
  int s = blockIdx.x, tid = threadIdx.x;
  for (int k = tid; k < NBUCK; k += 256) {
    unsigned gb = hist[(size_t)s * NBUCK + k];
    unsigned nb = (s == NSLICE - 1) ? start[k + 1]
                                    : hist[(size_t)(s + 1) * NBUCK + k];
    offA[k] = gb;
    A2[k] = nb - gb;
  }
  __syncthreads();
  // exclusive scan of A2 in place: contiguous 7 elems/thread + wave shfl +
  // cross-wave (2 barriers)
  {
    int lane = tid & 63, wid = tid >> 6;
    int t0 = tid * 7;
    unsigned v[7], run = 0;
#pragma unroll
    for (int m = 0; m < 7; ++m) {
      int k = t0 + m;
      v[m] = (k < NBUCK) ? A2[k] : 0u;
      run += v[m];
    }
    unsigned incl = run;
#pragma unroll
    for (int off = 1; off < 64; off <<= 1) {
      unsigned t = __shfl_up(incl, off);
      incl += (lane >= off) ? t : 0u;
    }
    if (lane == 63) tsum[wid] = incl;
    __syncthreads();
    unsigned wbase = 0;
    for (int w2 = 0; w2 < wid; ++w2) wbase += tsum[w2];
    unsigned acc = wbase + incl - run;  // exclusive prefix of elem t0
#pragma unroll
    for (int m = 0; m < 7; ++m) {
      int k = t0 + m;
      if (k < NBUCK) {
        offA[k] -= acc;
        A2[k] = acc;
        acc += v[m];
      }
    }
    __syncthreads();
  }
  int e0 = s * SLICE;
  for (int i = tid; i < SLICE; i += 256) {
    unsigned t = (unsigned)tgt[e0 + i];
    unsigned sr = (unsigned)src[e0 + i];
    unsigned b = t >> 6;
    unsigned lp = atomicAdd(&A2[b], 1u);
    stage[lp] = sr | ((t & 63u) << 17);
  }
  __syncthreads();
  for (int b = tid; b < NBUCK; b += 256) {
    unsigned beg = (b == 0) ? 0u : A2[b - 1];
    unsigned end = A2[b];
    unsigned go = offA[b];
    for (unsigned i = beg; i < end; ++i) payload[go + i] = stage[i];
  }
}

// ---------------- Encoder EdgeConv: 3-stage MFMA chain, nsplit-way --------
// min-waves hint 4 (not 8): 8 caps VGPR at 32 -> per-iter scratch spills
// (rounds 2-3: ~100 MB HBM traffic). Structure frozen at the R4 optimum;
// 5 structural variants (occupancy, prefetch depth, edges/iter, atomic
// shape, spill) all measured 98.5-101 us.
__global__ __launch_bounds__(256, 4) void enc_bucket(
    const float4* __restrict__ x, const unsigned* __restrict__ payload,
    const unsigned* __restrict__ start, const float* __restrict__ ab,
    const float* __restrict__ eb1, const float* __restrict__ eb2,
    const h2f16* __restrict__ wpk, float4* __restrict__ mvpart,
    float* __restrict__ cpart, int nsplit) {
  __shared__ float aM0[NB], aM1[NB], aV0[NB], aV1[NB], aC[NB];
  __shared__ float4 xt[NB];
  int k = blockIdx.x, node0 = k * NB, h = blockIdx.y;
  int tid = threadIdx.x, w = tid >> 6, lane = tid & 63;
  int q = lane >> 4, c = lane & 15;
  unsigned s0v = start[k], s1v = start[k + 1];
  unsigned len = s1v - s0v, qlen = (len + (unsigned)nsplit - 1u) / (unsigned)nsplit;
  unsigned lo = s0v + (unsigned)h * qlen;
  unsigned hi = lo + qlen;
  if (hi > s1v) hi = s1v;
  if (tid < NB) {
    int n = node0 + tid;
    aM0[tid] = 0; aM1[tid] = 0; aV0[tid] = 0; aV1[tid] = 0; aC[tid] = 0;
    xt[tid] = x[n < N_NODES ? n : 0];
  }
  __syncthreads();
  float a0 = ab[0], a1 = ab[1], a2 = ab[2], a3 = ab[3];
  float b0 = ab[4], b1 = ab[5], b2 = ab[6], b3 = ab[7];
  const u32x4* a2t = (const u32x4*)(wpk + PK_ENC_A2);
  const u32x4* a1t = (const u32x4*)(wpk + PK_ENC_A1);
  const u32x4* hat = (const u32x4*)(wpk + PK_ENC_HA);
  f16x8 A20 = __builtin_bit_cast(f16x8, a2t[lane]);
  f16x8 A21 = __builtin_bit_cast(f16x8, a2t[64 + lane]);
  f16x8 A10 = __builtin_bit_cast(f16x8, a1t[lane]);
  f16x8 A11 = __builtin_bit_cast(f16x8, a1t[64 + lane]);
  f16x8 HA = __builtin_bit_cast(f16x8, hat[lane]);
  float e1a[4], e1b[4], e2a[4], e2b[4];
#pragma unroll
  for (int r = 0; r < 4; ++r) {
    e1a[r] = eb1[4 * q + r];
    e1b[r] = eb1[16 + 4 * q + r];
    e2a[r] = eb2[4 * q + r];
    e2b[r] = eb2[16 + 4 * q + r];
  }
  unsigned base = lo + (unsigned)w * 32u;
  if (base < hi) {
    unsigned eA = base + (unsigned)c;
    eA = eA < hi ? eA : hi - 1u;
    unsigned eB = base + 16u + (unsigned)c;
    eB = eB < hi ? eB : hi - 1u;
    unsigned pA = payload[eA], pB = payload[eB];
    float4 xjA = x[(int)(pA & 0x1FFFFu)];
    float4 xjB = x[(int)(pB & 0x1FFFFu)];
    f32x4 zf = {0.f, 0.f, 0.f, 0.f};
    for (; base < hi; base += 128u) {
      // prefetch next iteration's payload (harmless clamped re-read at tail)
      unsigned nb = base + 128u;
      unsigned eAn = nb + (unsigned)c;
      eAn = eAn < hi ? eAn : hi - 1u;
      unsigned eBn = nb + 16u + (unsigned)c;
      eBn = eBn < hi ? eBn : hi - 1u;
      unsigned pAn = payload[eAn];
      unsigned pBn = payload[eBn];
      int ltiA = (int)(pA >> 17), ltiB = (int)(pB >> 17);
      float4 xiA = xt[ltiA], xiB = xt[ltiB];
      bool vA = (base + (unsigned)c) < hi;
      bool vB = (base + 16u + (unsigned)c) < hi;
      // features (k-slots 0..7 real for q==0; A1 zero-rows kill the rest)
      u32x4 fuA, fuB;
      fuA[0] = h2u(pk(fmaf(a0, xiA.x, b0), fmaf(a1, xiA.y, b1)));
      fuA[1] = h2u(pk(fmaf(a2, xiA.z, b2), fmaf(a3, xiA.w, b3)));
      fuA[2] = h2u(pk(a0 * (xjA.x - xiA.x), a1 * (xjA.y - xiA.y)));
      fuA[3] = h2u(pk(a2 * (xjA.z - xiA.z), a3 * (xjA.w - xiA.w)));
      fuB[0] = h2u(pk(fmaf(a0, xiB.x, b0), fmaf(a1, xiB.y, b1)));
      fuB[1] = h2u(pk(fmaf(a2, xiB.z, b2), fmaf(a3, xiB.w, b3)));
      fuB[2] = h2u(pk(a0 * (xjB.x - xiB.x), a1 * (xjB.y - xiB.y)));
      fuB[3] = h2u(pk(a2 * (xjB.z - xiB.z), a3 * (xjB.w - xiB.w)));
      // prefetch next x gathers while the MFMA chain runs
      float4 xjAn = x[(int)(pAn & 0x1FFFFu)];
      float4 xjBn = x[(int)(pBn & 0x1FFFFu)];
      f16x8 FA = __builtin_bit_cast(f16x8, fuA);
      f16x8 FB = __builtin_bit_cast(f16x8, fuB);
      // layer1 (K=8 zero-padded)
      f32x4 D10A = mfma16(A10, FA, zf), D11A = mfma16(A11, FA, zf);
      f32x4 D10B = mfma16(A10, FB, zf), D11B = mfma16(A11, FB, zf);
      // bias+relu, pack in tau order -> layer2 B-fragment (no shuffles)
      u32x4 h1A, h1B;
      h1A[0] = h2u(pk(fmaxf(D10A[0] + e1a[0], 0.f), fmaxf(D10A[1] + e1a[1], 0.f)));
      h1A[1] = h2u(pk(fmaxf(D10A[2] + e1a[2], 0.f), fmaxf(D10A[3] + e1a[3], 0.f)));
      h1A[2] = h2u(pk(fmaxf(D11A[0] + e1b[0], 0.f), fmaxf(D11A[1] + e1b[1], 0.f)));
      h1A[3] = h2u(pk(fmaxf(D11A[2] + e1b[2], 0.f), fmaxf(D11A[3] + e1b[3], 0.f)));
      h1B[0] = h2u(pk(fmaxf(D10B[0] + e1a[0], 0.f), fmaxf(D10B[1] + e1a[1], 0.f)));
      h1B[1] = h2u(pk(fmaxf(D10B[2] + e1a[2], 0.f), fmaxf(D10B[3] + e1a[3], 0.f)));
      h1B[2] = h2u(pk(fmaxf(D11B[0] + e1b[0], 0.f), fmaxf(D11B[1] + e1b[1], 0.f)));
      h1B[3] = h2u(pk(fmaxf(D11B[2] + e1b[2], 0.f), fmaxf(D11B[3] + e1b[3], 0.f)));
      f16x8 B2A = __builtin_bit_cast(f16x8, h1A);
      f16x8 B2B = __builtin_bit_cast(f16x8, h1B);
      // layer2 (A tau-permuted to match)
      f32x4 C0A = mfma16(A20, B2A, zf), C1A = mfma16(A21, B2A, zf);
      f32x4 C0B = mfma16(A20, B2B, zf), C1B = mfma16(A21, B2B, zf);
      // bias+relu, pack in tau order -> head B-fragment
      u32x4 g2A, g2B;
      g2A[0] = h2u(pk(fmaxf(C0A[0] + e2a[0], 0.f), fmaxf(C0A[1] + e2a[1], 0.f)));
      g2A[1] = h2u(pk(fmaxf(C0A[2] + e2a[2], 0.f), fmaxf(C0A[3] + e2a[3], 0.f)));
      g2A[2] = h2u(pk(fmaxf(C1A[0] + e2b[0], 0.f), fmaxf(C1A[1] + e2b[1], 0.f)));
      g2A[3] = h2u(pk(fmaxf(C1A[2] + e2b[2], 0.f), fmaxf(C1A[3] + e2b[3], 0.f)));
      g2B[0] = h2u(pk(fmaxf(C0B[0] + e2a[0], 0.f), fmaxf(C0B[1] + e2a[1], 0.f)));
      g2B[1] = h2u(pk(fmaxf(C0B[2] + e2a[2], 0.f), fmaxf(C0B[3] + e2a[3], 0.f)));
      g2B[2] = h2u(pk(fmaxf(C1B[0] + e2b[0], 0.f), fmaxf(C1B[1] + e2b[1], 0.f)));
      g2B[3] = h2u(pk(fmaxf(C1B[2] + e2b[2], 0.f), fmaxf(C1B[3] + e2b[3], 0.f)));
      // head MFMA: D2[out=r, edge=c] lands in q==0 lanes, regs 0..3
      f32x4 D2A = mfma16(HA, __builtin_bit_cast(f16x8, g2A), zf);
      f32x4 D2B = mfma16(HA, __builtin_bit_cast(f16x8, g2B), zf);
      if (lane < 16) {
        if (vA) {
          atomicAdd(&aM0[ltiA], D2A[0]);
          atomicAdd(&aM1[ltiA], D2A[1]);
          atomicAdd(&aV0[ltiA], D2A[2]);
          atomicAdd(&aV1[ltiA], D2A[3]);
          atomicAdd(&aC[ltiA], 1.0f);
        }
        if (vB) {
          atomicAdd(&aM0[ltiB], D2B[0]);
          atomicAdd(&aM1[ltiB], D2B[1]);
          atomicAdd(&aV0[ltiB], D2B[2]);
          atomicAdd(&aV1[ltiB], D2B[3]);
          atomicAdd(&aC[ltiB], 1.0f);
        }
      }
      pA = pAn; pB = pBn; xjA = xjAn; xjB = xjBn;
    }
  }
  __syncthreads();
  // plain-store partial slice (empty-range blocks store zeros; no memset,
  // no global atomics -> no line-granular RMW traffic)
  if (tid < NB) {
    int n = node0 + tid;
    if (n < N_NODES) {
      mvpart[(size_t)h * N_NODES + n] =
          make_float4(aM0[tid], aM1[tid], aV0[tid], aV1[tid]);
      cpart[(size_t)h * N_NODES + n] = aC[tid];
    }
  }
}

// ---------------- reduce partials + mean + bias + reparameterize ----------
__global__ __launch_bounds__(256) void node_mid(
    const float4* __restrict__ mvpart, const float* __restrict__ cpart,
    const float* __restrict__ eps2, const float* __restrict__ mbias,
    const float* __restrict__ vbias, float* __restrict__ z,
    float* __restrict__ cntC, float2* __restrict__ muOut,
    float2* __restrict__ lvOut, int nsplit) {
  int n = blockIdx.x * 256 + threadIdx.x;
  if (n >= N_NODES) return;
  float m0 = 0, m1 = 0, v0 = 0, v1 = 0, cc = 0;
  for (int h = 0; h < nsplit; ++h) {
    float4 t = mvpart[(size_t)h * N_NODES + n];
    m0 += t.x; m1 += t.y; v0 += t.z; v1 += t.w;
    cc += cpart[(size_t)h * N_NODES + n];
  }
  float inv = 1.0f / fmaxf(cc, 1.0f);
  float mu0 = fmaf(m0, inv, mbias[0]);
  float mu1 = fmaf(m1, inv, mbias[1]);
  float lv0 = fmaf(v0, inv, vbias[0]);
  float lv1 = fmaf(v1, inv, vbias[1]);
  cntC[n] = cc;
  muOut[n] = make_float2(mu0, mu1);
  lvOut[n] = make_float2(lv0, lv1);
  z[2 * n + 0] = fmaf(eps2[2 * n + 0], expf(0.5f * lv0), mu0);
  z[2 * n + 1] = fmaf(eps2[2 * n + 1], expf(0.5f * lv1), mu1);
}

// ---------------- Decoder EdgeConv: 3-stage MFMA chain, nsplit-way --------
__global__ __launch_bounds__(256, 4) void dec_bucket(
    const float2* __restrict__ z, const unsigned* __restrict__ payload,
    const unsigned* __restrict__ start, const float* __restrict__ db1,
    const float* __restrict__ db2, const h2f16* __restrict__ wpk,
    float4* __restrict__ opart, int nsplit) {
  __shared__ float aO0[NB], aO1[NB], aO2[NB], aO3[NB];
  __shared__ float2 zt[NB];
  int k = blockIdx.x, node0 = k * NB, h = blockIdx.y;
  int tid = threadIdx.x, w = tid >> 6, lane = tid & 63;
  int q = lane >> 4, c = lane & 15;
  unsigned s0v = start[k], s1v = start[k + 1];
  unsigned len = s1v - s0v, qlen = (len + (unsigned)nsplit - 1u) / (unsigned)nsplit;
  unsigned lo = s0v + (unsigned)h * qlen;
  unsigned hi = lo + qlen;
  if (hi > s1v) hi = s1v;
  if (tid < NB) {
    int n = node0 + tid;
    aO0[tid] = 0; aO1[tid] = 0; aO2[tid] = 0; aO3[tid] = 0;
    zt[tid] = z[n < N_NODES ? n : 0];
  }
  __syncthreads();
  const u32x4* a2t = (const u32x4*)(wpk + PK_DEC_A2);
  const u32x4* a1t = (const u32x4*)(wpk + PK_DEC_A1);
  const u32x4* hat = (const u32x4*)(wpk + PK_DEC_HA);
  f16x8 A20 = __builtin_bit_cast(f16x8, a2t[lane]);
  f16x8 A21 = __builtin_bit_cast(f16x8, a2t[64 + lane]);
  f16x8 A10 = __builtin_bit_cast(f16x8, a1t[lane]);
  f16x8 A11 = __builtin_bit_cast(f16x8, a1t[64 + lane]);
  f16x8 HA = __builtin_bit_cast(f16x8, hat[lane]);
  float e1a[4], e1b[4], e2a[4], e2b[4];
#pragma unroll
  for (int r = 0; r < 4; ++r) {
    e1a[r] = db1[4 * q + r];
    e1b[r] = db1[16 + 4 * q + r];
    e2a[r] = db2[4 * q + r];
    e2b[r] = db2[16 + 4 * q + r];
  }
  unsigned base = lo + (unsigned)w * 32u;
  if (base < hi) {
    unsigned eA = base + (unsigned)c;
    eA = eA < hi ? eA : hi - 1u;
    unsigned eB = base + 16u + (unsigned)c;
    eB = eB < hi ? eB : hi - 1u;
    unsigned pA = payload[eA], pB = payload[eB];
    float2 zjA = z[(int)(pA & 0x1FFFFu)];
    float2 zjB = z[(int)(pB & 0x1FFFFu)];
    f32x4 zf = {0.f, 0.f, 0.f, 0.f};
    for (; base < hi; base += 128u) {
      unsigned nb = base + 128u;
      unsigned eAn = nb + (unsigned)c;
      eAn = eAn < hi ? eAn : hi - 1u;
      unsigned eBn = nb + 16u + (unsigned)c;
      eBn = eBn < hi ? eBn : hi - 1u;
      unsigned pAn = payload[eAn];
      unsigned pBn = payload[eBn];
      int ltiA = (int)(pA >> 17), ltiB = (int)(pB >> 17);
      float2 ziA = zt[ltiA], ziB = zt[ltiB];
      bool vA = (base + (unsigned)c) < hi;
      bool vB = (base + 16u + (unsigned)c) < hi;
      // features: 4 real k-slots; upper slots junk (A1 zero-rows kill them)
      u32x4 fuA, fuB;
      fuA[0] = h2u(pk(ziA.x, ziA.y));
      fuA[1] = h2u(pk(zjA.x - ziA.x, zjA.y - ziA.y));
      fuA[2] = fuA[0];
      fuA[3] = fuA[1];
      fuB[0] = h2u(pk(ziB.x, ziB.y));
      fuB[1] = h2u(pk(zjB.x - ziB.x, zjB.y - ziB.y));
      fuB[2] = fuB[0];
      fuB[3] = fuB[1];
      float2 zjAn = z[(int)(pAn & 0x1FFFFu)];
      float2 zjBn = z[(int)(pBn & 0x1FFFFu)];
      f16x8 FA = __builtin_bit_cast(f16x8, fuA);
      f16x8 FB = __builtin_bit_cast(f16x8, fuB);
      f32x4 D10A = mfma16(A10, FA, zf), D11A = mfma16(A11, FA, zf);
      f32x4 D10B = mfma16(A10, FB, zf), D11B = mfma16(A11, FB, zf);
      u32x4 h1A, h1B;
      h1A[0] = h2u(pk(fmaxf(D10A[0] + e1a[0], 0.f), fmaxf(D10A[1] + e1a[1], 0.f)));
      h1A[1] = h2u(pk(fmaxf(D10A[2] + e1a[2], 0.f), fmaxf(D10A[3] + e1a[3], 0.f)));
      h1A[2] = h2u(pk(fmaxf(D11A[0] + e1b[0], 0.f), fmaxf(D11A[1] + e1b[1], 0.f)));
      h1A[3] = h2u(pk(fmaxf(D11A[2] + e1b[2], 0.f), fmaxf(D11A[3] + e1b[3], 0.f)));
      h1B[0] = h2u(pk(fmaxf(D10B[0] + e1a[0], 0.f), fmaxf(D10B[1] + e1a[1], 0.f)));
      h1B[1] = h2u(pk(fmaxf(D10B[2] + e1a[2], 0.f), fmaxf(D10B[3] + e1a[3], 0.f)));
      h1B[2] = h2u(pk(fmaxf(D11B[0] + e1b[0], 0.f), fmaxf(D11B[1] + e1b[1], 0.f)));
      h1B[3] = h2u(pk(fmaxf(D11B[2] + e1b[2], 0.f), fmaxf(D11B[3] + e1b[3], 0.f)));
      f16x8 B2A = __builtin_bit_cast(f16x8, h1A);
      f16x8 B2B = __builtin_bit_cast(f16x8, h1B);
      f32x4 C0A = mfma16(A20, B2A, zf), C1A = mfma16(A21, B2A, zf);
      f32x4 C0B = mfma16(A20, B2B, zf), C1B = mfma16(A21, B2B, zf);
      u32x4 g2A, g2B;
      g2A[0] = h2u(pk(fmaxf(C0A[0] + e2a[0], 0.f), fmaxf(C0A[1] + e2a[1], 0.f)));
      g2A[1] = h2u(pk(fmaxf(C0A[2] + e2a[2], 0.f), fmaxf(C0A[3] + e2a[3], 0.f)));
      g2A[2] = h2u(pk(fmaxf(C1A[0] + e2b[0], 0.f), fmaxf(C1A[1] + e2b[1], 0.f)));
      g2A[3] = h2u(pk(fmaxf(C1A[2] + e2b[2], 0.f), fmaxf(C1A[3] + e2b[3], 0.f)));
      g2B[0] = h2u(pk(fmaxf(C0B[0] + e2a[0], 0.f), fmaxf(C0B[1] + e2a[1], 0.f)));
      g2B[1] = h2u(pk(fmaxf(C0B[2] + e2a[2], 0.f), fmaxf(C0B[3] + e2a[3], 0.f)));
      g2B[2] = h2u(pk(fmaxf(C1B[0] + e2b[0], 0.f), fmaxf(C1B[1] + e2b[1], 0.f)));
      g2B[3] = h2u(pk(fmaxf(C1B[2] + e2b[2], 0.f), fmaxf(C1B[3] + e2b[3], 0.f)));
      f32x4 D2A = mfma16(HA, __builtin_bit_cast(f16x8, g2A), zf);
      f32x4 D2B = mfma16(HA, __builtin_bit_cast(f16x8, g2B), zf);
      if (lane < 16) {
        if (vA) {
          atomicAdd(&aO0[ltiA], D2A[0]);
          atomicAdd(&aO1[ltiA], D2A[1]);
          atomicAdd(&aO2[ltiA], D2A[2]);
          atomicAdd(&aO3[ltiA], D2A[3]);
        }
        if (vB) {
          atomicAdd(&aO0[ltiB], D2B[0]);
          atomicAdd(&aO1[ltiB], D2B[1]);
          atomicAdd(&aO2[ltiB], D2B[2]);
          atomicAdd(&aO3[ltiB], D2B[3]);
        }
      }
      pA = pAn; pB = pBn; zjA = zjAn; zjB = zjBn;
    }
  }
  __syncthreads();
  if (tid < NB) {
    int n = node0 + tid;
    if (n < N_NODES)
      opart[(size_t)h * N_NODES + n] =
          make_float4(aO0[tid], aO1[tid], aO2[tid], aO3[tid]);
  }
}

__global__ __launch_bounds__(256) void node_final(
    const float4* __restrict__ opart, const float* __restrict__ cntC,
    const float* __restrict__ db3, float4* __restrict__ outp, int nsplit) {
  int n = blockIdx.x * 256 + threadIdx.x;
  if (n >= N_NODES) return;
  float o0 = 0, o1 = 0, o2 = 0, o3 = 0;
  for (int h = 0; h < nsplit; ++h) {
    float4 t = opart[(size_t)h * N_NODES + n];
    o0 += t.x; o1 += t.y; o2 += t.z; o3 += t.w;
  }
  float cc = cntC[n];
  if (cc > 0.0f) {
    float inv = 1.0f / cc;
    outp[n] = make_float4(fmaf(o0, inv, db3[0]), fmaf(o1, inv, db3[1]),
                          fmaf(o2, inv, db3[2]), fmaf(o3, inv, db3[3]));
  } else {
    outp[n] = make_float4(0.f, 0.f, 0.f, 0.f);
  }
}

// ---------------- fallback (device-scope atomics, fp32, round-1 proven) ----
__global__ void bn_reduce(const float4* __restrict__ x, float* __restrict__ bns) {
  float s0 = 0, s1 = 0, s2 = 0, s3 = 0, q0 = 0, q1 = 0, q2 = 0, q3 = 0;
  for (int i = blockIdx.x * blockDim.x + threadIdx.x; i < N_NODES;
       i += gridDim.x * blockDim.x) {
    float4 v = x[i];
    s0 += v.x; s1 += v.y; s2 += v.z; s3 += v.w;
    q0 += v.x * v.x; q1 += v.y * v.y; q2 += v.z * v.z; q3 += v.w * v.w;
  }
#pragma unroll
  for (int o = 32; o; o >>= 1) {
    s0 += __shfl_down(s0, o); s1 += __shfl_down(s1, o);
    s2 += __shfl_down(s2, o); s3 += __shfl_down(s3, o);
    q0 += __shfl_down(q0, o); q1 += __shfl_down(q1, o);
    q2 += __shfl_down(q2, o); q3 += __shfl_down(q3, o);
  }
  __shared__ float red[4][8];
  int w = threadIdx.x >> 6;
  if ((threadIdx.x & 63) == 0) {
    red[w][0] = s0; red[w][1] = s1; red[w][2] = s2; red[w][3] = s3;
    red[w][4] = q0; red[w][5] = q1; red[w][6] = q2; red[w][7] = q3;
  }
  __syncthreads();
  if (threadIdx.x < 8) {
    float acc = red[0][threadIdx.x] + red[1][threadIdx.x] +
                red[2][threadIdx.x] + red[3][threadIdx.x];
    atomicAdd(&bns[threadIdx.x], acc);
  }
}

__global__ void bn_final(const float* __restrict__ bns,
                         const float* __restrict__ gamma,
                         const float* __restrict__ beta,
                         float* __restrict__ ab) {
  int d = threadIdx.x;
  if (d < 4) {
    float mean = bns[d] * (1.0f / N_NODES);
    float var = bns[4 + d] * (1.0f / N_NODES) - mean * mean;
    float a = gamma[d] * rsqrtf(var + 1e-5f);
    ab[d] = a;
    ab[4 + d] = beta[d] - mean * a;  // xn = a*x + b
  }
}

__global__ __launch_bounds__(256) void enc_edge_fb(
    const float4* __restrict__ x, const int* __restrict__ esrc,
    const int* __restrict__ etgt, const float* __restrict__ ab,
    const float* __restrict__ eW1, const float* __restrict__ eb1,
    const float* __restrict__ eW2, const float* __restrict__ eb2,
    const float* __restrict__ mW, const float* __restrict__ vW,
    float* __restrict__ msum, float* __restrict__ vsum,
    float* __restrict__ cnt) {
  int e = blockIdx.x * 256 + threadIdx.x;
  if (e >= N_EDGES) return;
  int si = esrc[e], ti = etgt[e];
  float4 xi = x[ti];
  float4 xj = x[si];
  float a0 = ab[0], a1 = ab[1], a2 = ab[2], a3 = ab[3];
  float b0 = ab[4], b1 = ab[5], b2 = ab[6], b3 = ab[7];
  float feat[8];
  feat[0] = fmaf(a0, xi.x, b0);
  feat[1] = fmaf(a1, xi.y, b1);
  feat[2] = fmaf(a2, xi.z, b2);
  feat[3] = fmaf(a3, xi.w, b3);
  feat[4] = a0 * (xj.x - xi.x);
  feat[5] = a1 * (xj.y - xi.y);
  feat[6] = a2 * (xj.z - xi.z);
  feat[7] = a3 * (xj.w - xi.w);
  float h1[32];
#pragma unroll 8
  for (int j = 0; j < 32; ++j) {
    float acc = eb1[j];
#pragma unroll
    for (int kk = 0; kk < 8; ++kk) acc = fmaf(feat[kk], eW1[kk * 32 + j], acc);
    h1[j] = fmaxf(acc, 0.0f);
  }
  float m0 = 0, m1 = 0, v0 = 0, v1 = 0;
#pragma unroll 4
  for (int j = 0; j < 32; ++j) {
    float acc = eb2[j];
#pragma unroll
    for (int kk = 0; kk < 32; ++kk) acc = fmaf(h1[kk], eW2[kk * 32 + j], acc);
    float h2 = fmaxf(acc, 0.0f);
    m0 = fmaf(h2, mW[j * 2 + 0], m0);
    m1 = fmaf(h2, mW[j * 2 + 1], m1);
    v0 = fmaf(h2, vW[j * 2 + 0], v0);
    v1 = fmaf(h2, vW[j * 2 + 1], v1);
  }
  atomAddF(&msum[ti * 2 + 0], m0);
  atomAddF(&msum[ti * 2 + 1], m1);
  atomAddF(&vsum[ti * 2 + 0], v0);
  atomAddF(&vsum[ti * 2 + 1], v1);
  atomAddF(&cnt[ti], 1.0f);
}

__global__ __launch_bounds__(256) void dec_edge_fb(
    const float2* __restrict__ z, const int* __restrict__ esrc,
    const int* __restrict__ etgt, const float* __restrict__ dW1,
    const float* __restrict__ db1, const float* __restrict__ dW2,
    const float* __restrict__ db2, const float* __restrict__ dW3,
    const float* __restrict__ db3, float* __restrict__ osum) {
  int e = blockIdx.x * 256 + threadIdx.x;
  if (e >= N_EDGES) return;
  int si = esrc[e], ti = etgt[e];
  float2 zi = z[ti], zj = z[si];
  float f0 = zi.x, f1 = zi.y, f2 = zj.x - zi.x, f3 = zj.y - zi.y;
  float h1[32];
#pragma unroll 8
  for (int j = 0; j < 32; ++j) {
    float acc = db1[j];
    acc = fmaf(f0, dW1[0 * 32 + j], acc);
    acc = fmaf(f1, dW1[1 * 32 + j], acc);
    acc = fmaf(f2, dW1[2 * 32 + j], acc);
    acc = fmaf(f3, dW1[3 * 32 + j], acc);
    h1[j] = fmaxf(acc, 0.0f);
  }
  float o0 = db3[0], o1 = db3[1], o2 = db3[2], o3 = db3[3];
#pragma unroll 4
  for (int j = 0; j < 32; ++j) {
    float acc = db2[j];
#pragma unroll
    for (int kk = 0; kk < 32; ++kk) acc = fmaf(h1[kk], dW2[kk * 32 + j], acc);
    float h2 = fmaxf(acc, 0.0f);
    o0 = fmaf(h2, dW3[j * 4 + 0], o0);
    o1 = fmaf(h2, dW3[j * 4 + 1], o1);
    o2 = fmaf(h2, dW3[j * 4 + 2], o2);
    o3 = fmaf(h2, dW3[j * 4 + 3], o3);
  }
  atomAddF(&osum[4 * ti + 0], o0);
  atomAddF(&osum[4 * ti + 1], o1);
  atomAddF(&osum[4 * ti + 2], o2);
  atomAddF(&osum[4 * ti + 3], o3);
}

__global__ __launch_bounds__(256) void node_mid_fb(
    float* __restrict__ msum, float* __restrict__ vsum,
    const float* __restrict__ cnt, const float* __restrict__ eps2,
    const float* __restrict__ mb, const float* __restrict__ vb,
    float* __restrict__ z) {
  int n = blockIdx.x * 256 + threadIdx.x;
  if (n >= N_NODES) return;
  float inv = 1.0f / fmaxf(cnt[n], 1.0f);
  float mu0 = fmaf(msum[2 * n + 0], inv, mb[0]);
  float mu1 = fmaf(msum[2 * n + 1], inv, mb[1]);
  float lv0 = fmaf(vsum[2 * n + 0], inv, vb[0]);
  float lv1 = fmaf(vsum[2 * n + 1], inv, vb[1]);
  msum[2 * n + 0] = mu0;
  msum[2 * n + 1] = mu1;
  vsum[2 * n + 0] = lv0;
  vsum[2 * n + 1] = lv1;
  z[2 * n + 0] = fmaf(eps2[2 * n + 0], expf(0.5f * lv0), mu0);
  z[2 * n + 1] = fmaf(eps2[2 * n + 1], expf(0.5f * lv1), mu1);
}

__global__ __launch_bounds__(256) void node_final_fb(
    float* __restrict__ osum, const float* __restrict__ cnt) {
  int n = blockIdx.x * 256 + threadIdx.x;
  if (n >= N_NODES) return;
  float inv = 1.0f / fmaxf(cnt[n], 1.0f);
  float4* o4 = (float4*)osum;
  float4 v = o4[n];
  v.x *= inv; v.y *= inv; v.z *= inv; v.w *= inv;
  o4[n] = v;
}

extern "C" void kernel_launch(void* const* d_in, const int* in_sizes, int n_in,
                              void* d_out, int out_size, void* d_ws,
                              size_t ws_size, hipStream_t stream) {
  const float* x = (const float*)d_in[0];
  const int* ei = (const int*)d_in[1];
  const float* eps = (const float*)d_in[2];
  const float* bng = (const float*)d_in[3];
  const float* bnb = (const float*)d_in[4];
  const float* eW1 = (const float*)d_in[5];
  const float* eb1 = (const float*)d_in[6];
  const float* eW2 = (const float*)d_in[7];
  const float* eb2 = (const float*)d_in[8];
  const float* mW = (const float*)d_in[9];
  const float* mb = (const float*)d_in[10];
  const float* vW = (const float*)d_in[11];
  const float* vb = (const float*)d_in[12];
  const float* dW1 = (const float*)d_in[13];
  const float* db1 = (const float*)d_in[14];
  const float* dW2 = (const float*)d_in[15];
  const float* db2 = (const float*)d_in[16];
  const float* dW3 = (const float*)d_in[17];
  const float* db3 = (const float*)d_in[18];

  float* out = (float*)d_out;  // [N,4] out | [N,2] mu | [N,2] logvar
  const size_t N = N_NODES;
  const size_t TOTPAD = 1568;  // NBUCK rounded up

  const size_t sortBytes =
      ((size_t)(NBUCK + 1) + (size_t)NSLICE * NBUCK + N_EDGES + PK_TOTAL) *
      sizeof(unsigned);
  // floats: 16 hdr + tot TOTPAD + z 2N + cntC N + mvpart 4sN + cpart sN +
  // opart 4sN
  auto reqFor = [&](int s) {
    return (16 + TOTPAD + 3 * N + 9 * (size_t)s * N) * sizeof(float) +
           sortBytes;
  };
  int ns = 0;
  if (ws_size >= reqFor(4)) ns = 4;
  else if (ws_size >= reqFor(2)) ns = 2;
  else if (ws_size >= reqFor(1)) ns = 1;

  float* wsf = (float*)d_ws;
  float* bns = wsf;                          // 8
  float* ab = wsf + 8;                       // 8
  unsigned* tot = (unsigned*)(wsf + 16);     // TOTPAD
  float* z = wsf + 16 + TOTPAD;              // 2N
  float* cntC = z + 2 * N;                   // N
  float4* mvpart = (float4*)(cntC + N);      // ns*N float4
  float* cpart = (float*)(mvpart + (size_t)ns * N);  // ns*N
  float4* opart = (float4*)(cpart + (size_t)ns * N); // ns*N float4
  unsigned* start = (unsigned*)((float*)opart + 4 * (size_t)ns * N);  // NBUCK+1
  unsigned* hist = start + (NBUCK + 1);                  // NSLICE*NBUCK
  unsigned* payload = hist + (size_t)NSLICE * NBUCK;     // N_EDGES
  h2f16* wpk = (h2f16*)(payload + N_EDGES);              // PK_TOTAL

  if (ns > 0) {
    // one memset: bns(8) + ab(8) + tot(TOTPAD), contiguous
    (void)hipMemsetAsync(wsf, 0, (16 + TOTPAD) * sizeof(float), stream);
    prep<<<NSLICE, 256, 0, stream>>>(ei + N_EDGES, (const float4*)x, eW1, eW2,
                                     mW, vW, dW1, dW2, dW3, hist, tot, bns,
                                     wpk);
    scan_init<<<1, 1024, 0, stream>>>(tot, start, bns, bng, bnb, ab);
    bucket_bases<<<(NBUCK + 3) / 4, 256, 0, stream>>>(hist, start);
    edge_place<<<NSLICE, 256, 0, stream>>>(ei, ei + N_EDGES, hist, start,
                                           payload);
    dim3 gE(NBUCK, ns);
    enc_bucket<<<gE, 256, 0, stream>>>((const float4*)x, payload, start, ab,
                                       eb1, eb2, wpk, mvpart, cpart, ns);
    node_mid<<<NBLK_NODE, 256, 0, stream>>>(mvpart, cpart, eps, mb, vb, z,
                                            cntC, (float2*)(out + 4 * N),
                                            (float2*)(out + 6 * N), ns);
    dec_bucket<<<gE, 256, 0, stream>>>((const float2*)z, payload, start, db1,
                                       db2, wpk, opart, ns);
    node_final<<<NBLK_NODE, 256, 0, stream>>>(opart, cntC, db3, (float4*)out,
                                              ns);
  } else {
    // fallback: device-scope atomics (round-1 proven path)
    float* cntf = wsf + 16;       // N
    float* zf = wsf + 16 + N;     // 2N
    float* msum = out + 4 * N;
    float* vsum = out + 6 * N;
    (void)hipMemsetAsync(d_out, 0, 8 * N * sizeof(float), stream);
    (void)hipMemsetAsync(d_ws, 0, (16 + N) * sizeof(float), stream);
    bn_reduce<<<256, 256, 0, stream>>>((const float4*)x, bns);
    bn_final<<<1, 64, 0, stream>>>(bns, bng, bnb, ab);
    enc_edge_fb<<<NBLK_EDGE, 256, 0, stream>>>((const float4*)x, ei,
                                               ei + N_EDGES, ab, eW1, eb1, eW2,
                                               eb2, mW, vW, msum, vsum, cntf);
    node_mid_fb<<<NBLK_NODE, 256, 0, stream>>>(msum, vsum, cntf, eps, mb, vb,
                                               zf);
    dec_edge_fb<<<NBLK_EDGE, 256, 0, stream>>>((const float2*)zf, ei,
                                               ei + N_EDGES, dW1, db1, dW2, db2,
                                               dW3, db3, out);
    node_final_fb<<<NBLK_NODE, 256, 0, stream>>>(out, cntf);
  }
}